// Round 1
// baseline (6137.166 us; speedup 1.0000x reference)
//
#include <hip/hip_runtime.h>

#define NNODES 100000
#define NEDGES 1600000
#define DIM 128
#define BN_EPS 1e-5f

// ---------------- setup: detect edge dtype (int64 vs int32) + zero stats ----
__global__ __launch_bounds__(256) void k_setup(const int* __restrict__ ei,
                                               float* __restrict__ stats,
                                               int* __restrict__ flag) {
    int t = threadIdx.x;
    if (t < 256) stats[t] = 0.0f;  // sums[128] + sumsq[128]
    if (t == 0) {
        // If edge_index is int64 (little-endian, values < 2^17), every odd
        // int32 word is the zero hi-word. If int32, these are random node ids.
        int orr = 0;
        for (int i = 1; i < 128; i += 2) orr |= ei[i];
        *flag = (orr == 0) ? 1 : 0;
    }
}

// ---------------- z = x (vector copy) ---------------------------------------
__global__ __launch_bounds__(256) void k_copy(const float* __restrict__ src,
                                              float* __restrict__ dst) {
    size_t i = (size_t)blockIdx.x * 256 + threadIdx.x;  // float4 index
    ((float4*)dst)[i] = ((const float4*)src)[i];
}

// ---------------- scatter-add: z[dst] += x[src] -----------------------------
__global__ __launch_bounds__(256) void k_scatter(const float* __restrict__ x,
                                                 float* __restrict__ z,
                                                 const int* __restrict__ ei,
                                                 const int* __restrict__ flag) {
    long long tid = (long long)blockIdx.x * 256 + threadIdx.x;
    int e  = (int)(tid >> 5);
    int c4 = ((int)tid & 31) * 4;
    int src, dst;
    if (*flag) { src = ei[2 * e];  dst = ei[2 * (NEDGES + e)]; }
    else       { src = ei[e];      dst = ei[NEDGES + e]; }
    float4 v = *(const float4*)(x + (size_t)src * DIM + c4);
    float* p = z + (size_t)dst * DIM + c4;
    unsafeAtomicAdd(p + 0, v.x);
    unsafeAtomicAdd(p + 1, v.y);
    unsafeAtomicAdd(p + 2, v.z);
    unsafeAtomicAdd(p + 3, v.w);
}

// ---------------- scatter-add with BN applied on the fly --------------------
__global__ __launch_bounds__(256) void k_scatter_bn(const float* __restrict__ hr,
                                                    float* __restrict__ z,
                                                    const int* __restrict__ ei,
                                                    const int* __restrict__ flag,
                                                    const float* __restrict__ scale,
                                                    const float* __restrict__ shift) {
    long long tid = (long long)blockIdx.x * 256 + threadIdx.x;
    int e  = (int)(tid >> 5);
    int c4 = ((int)tid & 31) * 4;
    int src, dst;
    if (*flag) { src = ei[2 * e];  dst = ei[2 * (NEDGES + e)]; }
    else       { src = ei[e];      dst = ei[NEDGES + e]; }
    float4 v  = *(const float4*)(hr + (size_t)src * DIM + c4);
    float4 sc = *(const float4*)(scale + c4);
    float4 sh = *(const float4*)(shift + c4);
    v.x = fmaf(v.x, sc.x, sh.x);
    v.y = fmaf(v.y, sc.y, sh.y);
    v.z = fmaf(v.z, sc.z, sh.z);
    v.w = fmaf(v.w, sc.w, sh.w);
    float* p = z + (size_t)dst * DIM + c4;
    unsafeAtomicAdd(p + 0, v.x);
    unsafeAtomicAdd(p + 1, v.y);
    unsafeAtomicAdd(p + 2, v.z);
    unsafeAtomicAdd(p + 3, v.w);
}

// ---------------- z2 = hr*scale + shift (BN self term) ----------------------
__global__ __launch_bounds__(256) void k_init_bn(const float* __restrict__ hr,
                                                 float* __restrict__ z,
                                                 const float* __restrict__ scale,
                                                 const float* __restrict__ shift) {
    size_t i = (size_t)blockIdx.x * 256 + threadIdx.x;  // float4 index
    int c4 = (int)(i & 31) * 4;
    float4 v  = ((const float4*)hr)[i];
    float4 sc = *(const float4*)(scale + c4);
    float4 sh = *(const float4*)(shift + c4);
    v.x = fmaf(v.x, sc.x, sh.x);
    v.y = fmaf(v.y, sc.y, sh.y);
    v.z = fmaf(v.z, sc.z, sh.z);
    v.w = fmaf(v.w, sc.w, sh.w);
    ((float4*)z)[i] = v;
}

// ---------------- BN finalize: scale/shift from sums ------------------------
__global__ void k_bn(float* stats, const float* __restrict__ gamma,
                     const float* __restrict__ beta) {
    int c = threadIdx.x;  // 128 threads
    float s  = stats[c];
    float sq = stats[128 + c];
    float mean = s / (float)NNODES;
    float var  = sq / (float)NNODES - mean * mean;
    float sc = gamma[c] * rsqrtf(var + BN_EPS);
    float sh = beta[c] - mean * sc;
    stats[c]       = sc;
    stats[128 + c] = sh;
}

// ---------------- fused 2-layer MLP: out = [relu](relu(Z@Wa+Ba)@Wb+Bb) ------
// 256 threads, 16 rows/block. LDS: 64+64+8+8+1 = 145 KB -> 1 block/CU.
template <bool STATS, bool RELU_OUT>
__global__ __launch_bounds__(256) void k_mlp(const float* __restrict__ Z,
                                             const float* __restrict__ Wa,
                                             const float* __restrict__ Ba,
                                             const float* __restrict__ Wb,
                                             const float* __restrict__ Bb,
                                             float* __restrict__ Out,
                                             float* __restrict__ stats) {
    __shared__ float Was[DIM * DIM];
    __shared__ float Wbs[DIM * DIM];
    __shared__ float zs[16 * DIM];
    __shared__ float mid[16 * DIM];
    __shared__ float lsum[DIM];
    __shared__ float lsq[DIM];

    int t = threadIdx.x;
    // stage both weight matrices (16384 floats each)
    for (int i = t * 4; i < DIM * DIM; i += 256 * 4) {
        *(float4*)&Was[i] = *(const float4*)&Wa[i];
        *(float4*)&Wbs[i] = *(const float4*)&Wb[i];
    }
    if (STATS && t < DIM) { lsum[t] = 0.0f; lsq[t] = 0.0f; }
    int row0 = blockIdx.x * 16;
    for (int i = t * 4; i < 16 * DIM; i += 256 * 4)
        *(float4*)&zs[i] = *(const float4*)&Z[(size_t)row0 * DIM + i];
    __syncthreads();

    int r  = t >> 4;         // 0..15
    int c0 = (t & 15) * 8;   // 0..120
    float acc[8];
#pragma unroll
    for (int j = 0; j < 8; ++j) acc[j] = Ba[c0 + j];
    for (int k = 0; k < DIM; ++k) {
        float a = zs[r * DIM + k];
#pragma unroll
        for (int j = 0; j < 8; ++j) acc[j] = fmaf(a, Was[k * DIM + c0 + j], acc[j]);
    }
#pragma unroll
    for (int j = 0; j < 8; ++j) mid[r * DIM + c0 + j] = fmaxf(acc[j], 0.0f);
    __syncthreads();

#pragma unroll
    for (int j = 0; j < 8; ++j) acc[j] = Bb[c0 + j];
    for (int k = 0; k < DIM; ++k) {
        float a = mid[r * DIM + k];
#pragma unroll
        for (int j = 0; j < 8; ++j) acc[j] = fmaf(a, Wbs[k * DIM + c0 + j], acc[j]);
    }
    if (RELU_OUT) {
#pragma unroll
        for (int j = 0; j < 8; ++j) acc[j] = fmaxf(acc[j], 0.0f);
    }
    float4 v0 = make_float4(acc[0], acc[1], acc[2], acc[3]);
    float4 v1 = make_float4(acc[4], acc[5], acc[6], acc[7]);
    *(float4*)&Out[(size_t)(row0 + r) * DIM + c0]     = v0;
    *(float4*)&Out[(size_t)(row0 + r) * DIM + c0 + 4] = v1;

    if (STATS) {
        __syncthreads();  // lsum/lsq zeroed before first barrier; ensure all zeroed
#pragma unroll
        for (int j = 0; j < 8; ++j) {
            atomicAdd(&lsum[c0 + j], acc[j]);
            atomicAdd(&lsq[c0 + j], acc[j] * acc[j]);
        }
        __syncthreads();
        if (t < DIM) {
            unsafeAtomicAdd(&stats[t], lsum[t]);
            unsafeAtomicAdd(&stats[DIM + t], lsq[t]);
        }
    }
}

extern "C" void kernel_launch(void* const* d_in, const int* in_sizes, int n_in,
                              void* d_out, int out_size, void* d_ws, size_t ws_size,
                              hipStream_t stream) {
    const float* x     = (const float*)d_in[0];
    const int*   ei    = (const int*)d_in[1];
    const float* w1a   = (const float*)d_in[2];
    const float* b1a   = (const float*)d_in[3];
    const float* w1b   = (const float*)d_in[4];
    const float* b1b   = (const float*)d_in[5];
    const float* gamma = (const float*)d_in[6];
    const float* beta  = (const float*)d_in[7];
    const float* w2a   = (const float*)d_in[8];
    const float* b2a   = (const float*)d_in[9];
    const float* w2b   = (const float*)d_in[10];
    const float* b2b   = (const float*)d_in[11];
    float* out = (float*)d_out;

    char*  ws    = (char*)d_ws;
    float* stats = (float*)ws;              // 256 floats: sums|sumsq -> scale|shift
    int*   flag  = (int*)(ws + 1024);
    float* zbuf  = (float*)(ws + 4096);     // N*D floats (51.2 MB)

    const int elemBlocks    = (NNODES * DIM / 4) / 256;    // 12500
    const int scatterBlocks = (NEDGES * 32) / 256;         // 200000
    const int mlpBlocks     = NNODES / 16;                 // 6250

    k_setup<<<1, 256, 0, stream>>>(ei, stats, flag);
    // conv1: z1 = x + scatter(x)
    k_copy<<<elemBlocks, 256, 0, stream>>>(x, zbuf);
    k_scatter<<<scatterBlocks, 256, 0, stream>>>(x, zbuf, ei, flag);
    // hr = relu(MLP1(z1)) -> d_out ; accumulate BN stats
    k_mlp<true, true><<<mlpBlocks, 256, 0, stream>>>(zbuf, w1a, b1a, w1b, b1b, out, stats);
    // BN params
    k_bn<<<1, 128, 0, stream>>>(stats, gamma, beta);
    // conv2: z2 = bn(hr) + scatter(bn(hr))
    k_init_bn<<<elemBlocks, 256, 0, stream>>>(out, zbuf, stats, stats + DIM);
    k_scatter_bn<<<scatterBlocks, 256, 0, stream>>>(out, zbuf, ei, flag, stats, stats + DIM);
    // out = MLP2(z2)
    k_mlp<false, false><<<mlpBlocks, 256, 0, stream>>>(zbuf, w2a, b2a, w2b, b2b, out, nullptr);
}

// Round 2
// 1192.054 us; speedup vs baseline: 5.1484x; 5.1484x over previous
//
#include <hip/hip_runtime.h>

#define NNODES 100000
#define NEDGES 1600000
#define DIM 128
#define BN_EPS 1e-5f

// ---- edge access helper: flag=1 -> int64 layout, flag=0 -> int32 -----------
__device__ __forceinline__ int edge_src(const int* ei, int fl, int e) {
    return fl ? ei[2 * e] : ei[e];
}
__device__ __forceinline__ int edge_dst(const int* ei, int fl, int e) {
    return fl ? ei[2 * (NEDGES + e)] : ei[NEDGES + e];
}

// ---------------- setup: detect edge dtype (int64 vs int32) + zero stats ----
__global__ __launch_bounds__(256) void k_setup(const int* __restrict__ ei,
                                               float* __restrict__ stats,
                                               int* __restrict__ flag) {
    int t = threadIdx.x;
    if (t < 256) stats[t] = 0.0f;  // sums[128] + sumsq[128]
    if (t == 0) {
        // int64 little-endian with values < 2^17 -> every odd word is zero.
        int orr = 0;
        for (int i = 1; i < 128; i += 2) orr |= ei[i];
        *flag = (orr == 0) ? 1 : 0;
    }
}

// ---------------- zero the histogram ----------------------------------------
__global__ __launch_bounds__(1024) void k_zero(int* __restrict__ H) {
    int i = blockIdx.x * 1024 + threadIdx.x;
    if (i < NNODES) H[i] = 0;
}

// ---------------- histogram of dst ------------------------------------------
__global__ __launch_bounds__(256) void k_hist(const int* __restrict__ ei,
                                              const int* __restrict__ flag,
                                              int* __restrict__ H) {
    int fl = *flag;
    for (int e = blockIdx.x * 256 + threadIdx.x; e < NEDGES; e += gridDim.x * 256)
        atomicAdd(&H[edge_dst(ei, fl, e)], 1);
}

// ---------------- single-block exclusive scan: C = exscan(H) ----------------
__global__ __launch_bounds__(1024) void k_scan(const int* __restrict__ H,
                                               int* __restrict__ C) {
    __shared__ int wsum[16];
    __shared__ int carry;
    int t = threadIdx.x, lane = t & 63, w = t >> 6;
    if (t == 0) carry = 0;
    __syncthreads();
    for (int base = 0; base < NNODES; base += 1024) {
        int i = base + t;
        int v = (i < NNODES) ? H[i] : 0;
        int s = v;
#pragma unroll
        for (int d = 1; d < 64; d <<= 1) {
            int n = __shfl_up(s, d, 64);
            if (lane >= d) s += n;
        }
        if (lane == 63) wsum[w] = s;
        __syncthreads();
        if (w == 0 && lane < 16) {
            int x = wsum[lane];
#pragma unroll
            for (int d = 1; d < 16; d <<= 1) {
                int n = __shfl_up(x, d, 64);
                if (lane >= d) x += n;
            }
            wsum[lane] = x;
        }
        __syncthreads();
        int excl = carry + (w ? wsum[w - 1] : 0) + (s - v);
        if (i < NNODES) C[i] = excl;
        __syncthreads();
        if (t == 0) carry += wsum[15];
        __syncthreads();
    }
}

// ---------------- place edges: sorted_src grouped by dst --------------------
// Mutates C: afterwards C[i] = end offset of bin i (start = C[i-1]).
__global__ __launch_bounds__(256) void k_place(const int* __restrict__ ei,
                                               const int* __restrict__ flag,
                                               int* __restrict__ C,
                                               int* __restrict__ ssrc) {
    int fl = *flag;
    for (int e = blockIdx.x * 256 + threadIdx.x; e < NEDGES; e += gridDim.x * 256) {
        int s = edge_src(ei, fl, e);
        int d = edge_dst(ei, fl, e);
        int pos = atomicAdd(&C[d], 1);
        ssrc[pos] = s;
    }
}

// ---------------- gather-aggregate: Z[i] = f(X[i]) + sum_j f(X[src_j]) ------
// f = identity (BN=false) or x*scale+shift (BN=true). 32 lanes per row.
template <bool BN>
__global__ __launch_bounds__(256) void k_agg(const float* __restrict__ X,
                                             float* __restrict__ Z,
                                             const int* __restrict__ ends,
                                             const int* __restrict__ ssrc,
                                             const float* __restrict__ scale,
                                             const float* __restrict__ shift) {
    int t = threadIdx.x;
    int g = t >> 5;          // 0..7 row group
    int l = t & 31;
    int row = blockIdx.x * 8 + g;
    int c4 = l * 4;
    int start = (row == 0) ? 0 : ends[row - 1];
    int end = ends[row];

    float4 sc, sh;
    if (BN) {
        sc = *(const float4*)(scale + c4);
        sh = *(const float4*)(shift + c4);
    }
    float4 acc = *(const float4*)(X + (size_t)row * DIM + c4);
    if (BN) {
        acc.x = fmaf(acc.x, sc.x, sh.x);
        acc.y = fmaf(acc.y, sc.y, sh.y);
        acc.z = fmaf(acc.z, sc.z, sh.z);
        acc.w = fmaf(acc.w, sc.w, sh.w);
    }
    int e = start;
    for (; e + 3 < end; e += 4) {
        int s0 = ssrc[e], s1 = ssrc[e + 1], s2 = ssrc[e + 2], s3 = ssrc[e + 3];
        float4 v0 = *(const float4*)(X + (size_t)s0 * DIM + c4);
        float4 v1 = *(const float4*)(X + (size_t)s1 * DIM + c4);
        float4 v2 = *(const float4*)(X + (size_t)s2 * DIM + c4);
        float4 v3 = *(const float4*)(X + (size_t)s3 * DIM + c4);
        float4 u;
        u.x = (v0.x + v1.x) + (v2.x + v3.x);
        u.y = (v0.y + v1.y) + (v2.y + v3.y);
        u.z = (v0.z + v1.z) + (v2.z + v3.z);
        u.w = (v0.w + v1.w) + (v2.w + v3.w);
        if (BN) {
            acc.x = fmaf(u.x, sc.x, fmaf(4.0f, sh.x, acc.x));
            acc.y = fmaf(u.y, sc.y, fmaf(4.0f, sh.y, acc.y));
            acc.z = fmaf(u.z, sc.z, fmaf(4.0f, sh.z, acc.z));
            acc.w = fmaf(u.w, sc.w, fmaf(4.0f, sh.w, acc.w));
        } else {
            acc.x += u.x; acc.y += u.y; acc.z += u.z; acc.w += u.w;
        }
    }
    for (; e < end; ++e) {
        int s0 = ssrc[e];
        float4 v = *(const float4*)(X + (size_t)s0 * DIM + c4);
        if (BN) {
            acc.x = fmaf(v.x, sc.x, sh.x + acc.x);
            acc.y = fmaf(v.y, sc.y, sh.y + acc.y);
            acc.z = fmaf(v.z, sc.z, sh.z + acc.z);
            acc.w = fmaf(v.w, sc.w, sh.w + acc.w);
        } else {
            acc.x += v.x; acc.y += v.y; acc.z += v.z; acc.w += v.w;
        }
    }
    *(float4*)(Z + (size_t)row * DIM + c4) = acc;
}

// ---------------- BN finalize: scale/shift from sums ------------------------
__global__ void k_bn(float* stats, const float* __restrict__ gamma,
                     const float* __restrict__ beta) {
    int c = threadIdx.x;  // 128 threads
    float s  = stats[c];
    float sq = stats[128 + c];
    float mean = s / (float)NNODES;
    float var  = sq / (float)NNODES - mean * mean;
    float sc = gamma[c] * rsqrtf(var + BN_EPS);
    float sh = beta[c] - mean * sc;
    stats[c]       = sc;
    stats[128 + c] = sh;
}

// ---------------- fused 2-layer MLP: out = [relu](relu(Z@Wa+Ba)@Wb+Bb) ------
// 256 threads, 16 rows/block. LDS: 64 + 8 + 1 KB -> 2 blocks/CU.
template <bool STATS, bool RELU_OUT>
__global__ __launch_bounds__(256) void k_mlp(const float* __restrict__ Z,
                                             const float* __restrict__ Wa,
                                             const float* __restrict__ Ba,
                                             const float* __restrict__ Wb,
                                             const float* __restrict__ Bb,
                                             float* __restrict__ Out,
                                             float* __restrict__ stats) {
    __shared__ float Ws[DIM * DIM];   // Wa, then Wb
    __shared__ float zs[16 * DIM];    // z rows, then mid rows
    __shared__ float lsum[DIM];
    __shared__ float lsq[DIM];

    int t = threadIdx.x;
    for (int i = t * 4; i < DIM * DIM; i += 256 * 4)
        *(float4*)&Ws[i] = *(const float4*)&Wa[i];
    if (STATS && t < DIM) { lsum[t] = 0.0f; lsq[t] = 0.0f; }
    int row0 = blockIdx.x * 16;
    for (int i = t * 4; i < 16 * DIM; i += 256 * 4)
        *(float4*)&zs[i] = *(const float4*)&Z[(size_t)row0 * DIM + i];
    __syncthreads();

    int r  = t >> 4;         // 0..15
    int c0 = (t & 15) * 8;   // 0..120
    float acc[8];
#pragma unroll
    for (int j = 0; j < 8; ++j) acc[j] = Ba[c0 + j];
    for (int k = 0; k < DIM; ++k) {
        float a = zs[r * DIM + k];
#pragma unroll
        for (int j = 0; j < 8; ++j) acc[j] = fmaf(a, Ws[k * DIM + c0 + j], acc[j]);
    }
    float mid[8];
#pragma unroll
    for (int j = 0; j < 8; ++j) mid[j] = fmaxf(acc[j], 0.0f);
    __syncthreads();   // done reading zs + Ws

    // overwrite zs with mid, Ws with Wb
#pragma unroll
    for (int j = 0; j < 8; j += 4)
        *(float4*)&zs[r * DIM + c0 + j] = *(float4*)&mid[j];
    for (int i = t * 4; i < DIM * DIM; i += 256 * 4)
        *(float4*)&Ws[i] = *(const float4*)&Wb[i];
    __syncthreads();

#pragma unroll
    for (int j = 0; j < 8; ++j) acc[j] = Bb[c0 + j];
    for (int k = 0; k < DIM; ++k) {
        float a = zs[r * DIM + k];
#pragma unroll
        for (int j = 0; j < 8; ++j) acc[j] = fmaf(a, Ws[k * DIM + c0 + j], acc[j]);
    }
    if (RELU_OUT) {
#pragma unroll
        for (int j = 0; j < 8; ++j) acc[j] = fmaxf(acc[j], 0.0f);
    }
    *(float4*)&Out[(size_t)(row0 + r) * DIM + c0]     = make_float4(acc[0], acc[1], acc[2], acc[3]);
    *(float4*)&Out[(size_t)(row0 + r) * DIM + c0 + 4] = make_float4(acc[4], acc[5], acc[6], acc[7]);

    if (STATS) {
#pragma unroll
        for (int j = 0; j < 8; ++j) {
            atomicAdd(&lsum[c0 + j], acc[j]);
            atomicAdd(&lsq[c0 + j], acc[j] * acc[j]);
        }
        __syncthreads();
        if (t < DIM) {
            unsafeAtomicAdd(&stats[t], lsum[t]);
            unsafeAtomicAdd(&stats[DIM + t], lsq[t]);
        }
    }
}

extern "C" void kernel_launch(void* const* d_in, const int* in_sizes, int n_in,
                              void* d_out, int out_size, void* d_ws, size_t ws_size,
                              hipStream_t stream) {
    const float* x     = (const float*)d_in[0];
    const int*   ei    = (const int*)d_in[1];
    const float* w1a   = (const float*)d_in[2];
    const float* b1a   = (const float*)d_in[3];
    const float* w1b   = (const float*)d_in[4];
    const float* b1b   = (const float*)d_in[5];
    const float* gamma = (const float*)d_in[6];
    const float* beta  = (const float*)d_in[7];
    const float* w2a   = (const float*)d_in[8];
    const float* b2a   = (const float*)d_in[9];
    const float* w2b   = (const float*)d_in[10];
    const float* b2b   = (const float*)d_in[11];
    float* out = (float*)d_out;

    char*  ws    = (char*)d_ws;
    float* stats = (float*)ws;                 // 256 floats
    int*   flag  = (int*)(ws + 1024);
    int*   H     = (int*)(ws + 4096);          // N ints (histogram)
    int*   C     = (int*)(ws + 404096);        // N ints (scan -> cursors -> ends)
    int*   ssrc  = (int*)(ws + 804096);        // E ints (CSR sources)
    float* zbuf  = (float*)(ws + 8388608);     // N*D floats (51.2 MB)

    const int aggBlocks = NNODES / 8;          // 12500
    const int mlpBlocks = NNODES / 16;         // 6250

    // ---- build CSR once (shared by both convs) ----
    k_setup<<<1, 256, 0, stream>>>(ei, stats, flag);
    k_zero<<<(NNODES + 1023) / 1024, 1024, 0, stream>>>(H);
    k_hist<<<2048, 256, 0, stream>>>(ei, flag, H);
    k_scan<<<1, 1024, 0, stream>>>(H, C);
    k_place<<<2048, 256, 0, stream>>>(ei, flag, C, ssrc);
    // ---- conv1 ----
    k_agg<false><<<aggBlocks, 256, 0, stream>>>(x, zbuf, C, ssrc, nullptr, nullptr);
    k_mlp<true, true><<<mlpBlocks, 256, 0, stream>>>(zbuf, w1a, b1a, w1b, b1b, out, stats);
    // ---- BN params ----
    k_bn<<<1, 128, 0, stream>>>(stats, gamma, beta);
    // ---- conv2 (BN fused into aggregate) ----
    k_agg<true><<<aggBlocks, 256, 0, stream>>>(out, zbuf, C, ssrc, stats, stats + DIM);
    k_mlp<false, false><<<mlpBlocks, 256, 0, stream>>>(zbuf, w2a, b2a, w2b, b2b, out, nullptr);
}

// Round 3
// 812.214 us; speedup vs baseline: 7.5561x; 1.4677x over previous
//
#include <hip/hip_runtime.h>

#define NNODES 100000
#define NEDGES 1600000
#define DIM 128
#define BN_EPS 1e-5f

typedef unsigned int uint;
typedef unsigned short ushort_t;
using bhalf8  = __attribute__((ext_vector_type(8))) short;
using f32x4_t = __attribute__((ext_vector_type(4))) float;

// ---- edge access helper: flag=1 -> int64 layout, flag=0 -> int32 -----------
__device__ __forceinline__ int edge_src(const int* ei, int fl, int e) {
    return fl ? ei[2 * e] : ei[e];
}
__device__ __forceinline__ int edge_dst(const int* ei, int fl, int e) {
    return fl ? ei[2 * (NEDGES + e)] : ei[NEDGES + e];
}

// ---------------- setup: detect edge dtype (int64 vs int32) + zero stats ----
__global__ __launch_bounds__(256) void k_setup(const int* __restrict__ ei,
                                               float* __restrict__ stats,
                                               int* __restrict__ flag) {
    int t = threadIdx.x;
    if (t < 256) stats[t] = 0.0f;  // sums[128] + sumsq[128]
    if (t == 0) {
        int orr = 0;
        for (int i = 1; i < 128; i += 2) orr |= ei[i];
        *flag = (orr == 0) ? 1 : 0;
    }
}

// ---------------- zero the histogram ----------------------------------------
__global__ __launch_bounds__(1024) void k_zero(int* __restrict__ H) {
    int i = blockIdx.x * 1024 + threadIdx.x;
    if (i < NNODES) H[i] = 0;
}

// ---------------- histogram of dst ------------------------------------------
__global__ __launch_bounds__(256) void k_hist(const int* __restrict__ ei,
                                              const int* __restrict__ flag,
                                              int* __restrict__ H) {
    int fl = *flag;
    for (int e = blockIdx.x * 256 + threadIdx.x; e < NEDGES; e += gridDim.x * 256)
        atomicAdd(&H[edge_dst(ei, fl, e)], 1);
}

// ---------------- single-block exclusive scan: C = exscan(H) ----------------
__global__ __launch_bounds__(1024) void k_scan(const int* __restrict__ H,
                                               int* __restrict__ C) {
    __shared__ int wsum[16];
    __shared__ int carry;
    int t = threadIdx.x, lane = t & 63, w = t >> 6;
    if (t == 0) carry = 0;
    __syncthreads();
    for (int base = 0; base < NNODES; base += 1024) {
        int i = base + t;
        int v = (i < NNODES) ? H[i] : 0;
        int s = v;
#pragma unroll
        for (int d = 1; d < 64; d <<= 1) {
            int n = __shfl_up(s, d, 64);
            if (lane >= d) s += n;
        }
        if (lane == 63) wsum[w] = s;
        __syncthreads();
        if (w == 0 && lane < 16) {
            int x = wsum[lane];
#pragma unroll
            for (int d = 1; d < 16; d <<= 1) {
                int n = __shfl_up(x, d, 64);
                if (lane >= d) x += n;
            }
            wsum[lane] = x;
        }
        __syncthreads();
        int excl = carry + (w ? wsum[w - 1] : 0) + (s - v);
        if (i < NNODES) C[i] = excl;
        __syncthreads();
        if (t == 0) carry += wsum[15];
        __syncthreads();
    }
}

// ---------------- place edges: sorted_src grouped by dst --------------------
__global__ __launch_bounds__(256) void k_place(const int* __restrict__ ei,
                                               const int* __restrict__ flag,
                                               int* __restrict__ C,
                                               int* __restrict__ ssrc) {
    int fl = *flag;
    for (int e = blockIdx.x * 256 + threadIdx.x; e < NEDGES; e += gridDim.x * 256) {
        int s = edge_src(ei, fl, e);
        int d = edge_dst(ei, fl, e);
        int pos = atomicAdd(&C[d], 1);
        ssrc[pos] = s;
    }
}

// ---------------- weight prep: fp32 [k][n] -> bf16 hi/lo transposed [n][k] --
__global__ __launch_bounds__(256) void k_wprep(const float* __restrict__ w0,
                                               const float* __restrict__ w1,
                                               const float* __restrict__ w2,
                                               const float* __restrict__ w3,
                                               ushort_t* __restrict__ ob) {
    const float* w = (blockIdx.x == 0) ? w0 : (blockIdx.x == 1) ? w1
                   : (blockIdx.x == 2) ? w2 : w3;
    ushort_t* oh = ob + (size_t)blockIdx.x * 32768;
    ushort_t* ol = oh + 16384;
    for (int i = threadIdx.x; i < 16384; i += 256) {
        int k = i >> 7, n = i & 127;
        float v = w[i];
        uint u = __float_as_uint(v);
        uint r = u + 0x7FFFu + ((u >> 16) & 1u);   // RN to bf16
        ushort_t h = (ushort_t)(r >> 16);
        float hf = __uint_as_float(((uint)h) << 16);
        float lo = v - hf;
        uint u2 = __float_as_uint(lo);
        uint r2 = u2 + 0x7FFFu + ((u2 >> 16) & 1u);
        ushort_t lb = (ushort_t)(r2 >> 16);
        oh[n * 128 + k] = h;
        ol[n * 128 + k] = lb;
    }
}

// ---------------- split 8 fp32 -> bf16 hi (trunc) + bf16 lo (trunc) ---------
__device__ __forceinline__ void split8(const float4& f0, const float4& f1,
                                       bhalf8& h, bhalf8& l) {
    uint u[8] = { __float_as_uint(f0.x), __float_as_uint(f0.y),
                  __float_as_uint(f0.z), __float_as_uint(f0.w),
                  __float_as_uint(f1.x), __float_as_uint(f1.y),
                  __float_as_uint(f1.z), __float_as_uint(f1.w) };
    float fv[8] = { f0.x, f0.y, f0.z, f0.w, f1.x, f1.y, f1.z, f1.w };
    uint lu[8];
#pragma unroll
    for (int i = 0; i < 8; ++i) {
        float hf = __uint_as_float(u[i] & 0xffff0000u);
        lu[i] = __float_as_uint(fv[i] - hf);
    }
    union { uint4 q; bhalf8 s; } H, L;
    H.q.x = __builtin_amdgcn_perm(u[1], u[0], 0x07060302u);
    H.q.y = __builtin_amdgcn_perm(u[3], u[2], 0x07060302u);
    H.q.z = __builtin_amdgcn_perm(u[5], u[4], 0x07060302u);
    H.q.w = __builtin_amdgcn_perm(u[7], u[6], 0x07060302u);
    L.q.x = __builtin_amdgcn_perm(lu[1], lu[0], 0x07060302u);
    L.q.y = __builtin_amdgcn_perm(lu[3], lu[2], 0x07060302u);
    L.q.z = __builtin_amdgcn_perm(lu[5], lu[4], 0x07060302u);
    L.q.w = __builtin_amdgcn_perm(lu[7], lu[6], 0x07060302u);
    h = H.s; l = L.s;
}

// ---------------- gather-aggregate: Z[i] = f(X[i]) + sum_j f(X[src_j]) ------
template <bool BN>
__global__ __launch_bounds__(256) void k_agg(const float* __restrict__ X,
                                             float* __restrict__ Z,
                                             const int* __restrict__ ends,
                                             const int* __restrict__ ssrc,
                                             const float* __restrict__ scale,
                                             const float* __restrict__ shift) {
    int t = threadIdx.x;
    int g = t >> 5;          // 0..7 row group
    int l = t & 31;
    int row = blockIdx.x * 8 + g;
    int c4 = l * 4;
    int start = (row == 0) ? 0 : ends[row - 1];
    int end = ends[row];

    float4 sc, sh;
    if (BN) {
        sc = *(const float4*)(scale + c4);
        sh = *(const float4*)(shift + c4);
    }
    float4 acc = *(const float4*)(X + (size_t)row * DIM + c4);
    if (BN) {
        acc.x = fmaf(acc.x, sc.x, sh.x);
        acc.y = fmaf(acc.y, sc.y, sh.y);
        acc.z = fmaf(acc.z, sc.z, sh.z);
        acc.w = fmaf(acc.w, sc.w, sh.w);
    }
    int e = start;
    for (; e + 3 < end; e += 4) {
        int s0 = ssrc[e], s1 = ssrc[e + 1], s2 = ssrc[e + 2], s3 = ssrc[e + 3];
        float4 v0 = *(const float4*)(X + (size_t)s0 * DIM + c4);
        float4 v1 = *(const float4*)(X + (size_t)s1 * DIM + c4);
        float4 v2 = *(const float4*)(X + (size_t)s2 * DIM + c4);
        float4 v3 = *(const float4*)(X + (size_t)s3 * DIM + c4);
        float4 u;
        u.x = (v0.x + v1.x) + (v2.x + v3.x);
        u.y = (v0.y + v1.y) + (v2.y + v3.y);
        u.z = (v0.z + v1.z) + (v2.z + v3.z);
        u.w = (v0.w + v1.w) + (v2.w + v3.w);
        if (BN) {
            acc.x = fmaf(u.x, sc.x, fmaf(4.0f, sh.x, acc.x));
            acc.y = fmaf(u.y, sc.y, fmaf(4.0f, sh.y, acc.y));
            acc.z = fmaf(u.z, sc.z, fmaf(4.0f, sh.z, acc.z));
            acc.w = fmaf(u.w, sc.w, fmaf(4.0f, sh.w, acc.w));
        } else {
            acc.x += u.x; acc.y += u.y; acc.z += u.z; acc.w += u.w;
        }
    }
    for (; e < end; ++e) {
        int s0 = ssrc[e];
        float4 v = *(const float4*)(X + (size_t)s0 * DIM + c4);
        if (BN) {
            acc.x = fmaf(v.x, sc.x, sh.x + acc.x);
            acc.y = fmaf(v.y, sc.y, sh.y + acc.y);
            acc.z = fmaf(v.z, sc.z, sh.z + acc.z);
            acc.w = fmaf(v.w, sc.w, sh.w + acc.w);
        } else {
            acc.x += v.x; acc.y += v.y; acc.z += v.z; acc.w += v.w;
        }
    }
    *(float4*)(Z + (size_t)row * DIM + c4) = acc;
}

// ---------------- BN finalize: scale/shift from sums ------------------------
__global__ void k_bn(float* stats, const float* __restrict__ gamma,
                     const float* __restrict__ beta) {
    int c = threadIdx.x;  // 128 threads
    float s  = stats[c];
    float sq = stats[128 + c];
    float mean = s / (float)NNODES;
    float var  = sq / (float)NNODES - mean * mean;
    float sc = gamma[c] * rsqrtf(var + BN_EPS);
    float sh = beta[c] - mean * sc;
    stats[c]       = sc;
    stats[128 + c] = sh;
}

// ---------------- fused 2-layer MLP via split-bf16 MFMA ---------------------
// Block = 64 rows, 4 waves; wave = 16 rows x 128 cols (8 col-tiles of 16).
// 3-term split (zh*wh + zl*wh + zh*wl) keeps ~fp32 accuracy at MFMA rate.
template <bool STATS, bool RELU_OUT>
__global__ __launch_bounds__(256) void k_mlp(const float* __restrict__ Z,
                                             const ushort_t* __restrict__ WA, // hi, lo at +16384
                                             const ushort_t* __restrict__ WB,
                                             const float* __restrict__ Ba,
                                             const float* __restrict__ Bb,
                                             float* __restrict__ Out,
                                             float* __restrict__ stats) {
    __shared__ float hbuf[64 * 128];   // mid activations, XOR-swizzled
    __shared__ float lsum[128], lsq[128];

    int t = threadIdx.x;
    int w = t >> 6, l = t & 63;
    int lr = l & 15;        // row-in-tile (A) / col-in-tile (B,D)
    int lg = l >> 4;        // k-group
    if (STATS && t < 128) { lsum[t] = 0.f; lsq[t] = 0.f; }

    int rowBase = blockIdx.x * 64 + w * 16;
    bool active = rowBase < NNODES;

    // ---- layer 1: mid = relu(Z @ Wa + Ba) ----
    f32x4_t acc[8];
#pragma unroll
    for (int nt = 0; nt < 8; ++nt) {
        float b = Ba[nt * 16 + lr];
        acc[nt][0] = b; acc[nt][1] = b; acc[nt][2] = b; acc[nt][3] = b;
    }
    const ushort_t* wah = WA;
    const ushort_t* wal = WA + 16384;
    int zrow = active ? (rowBase + lr) : 0;
    const float* zp = Z + (size_t)zrow * 128 + lg * 8;
#pragma unroll
    for (int ks = 0; ks < 4; ++ks) {
        float4 f0 = *(const float4*)(zp + ks * 32);
        float4 f1 = *(const float4*)(zp + ks * 32 + 4);
        bhalf8 zh, zl; split8(f0, f1, zh, zl);
        int k0 = ks * 32 + lg * 8;
#pragma unroll
        for (int nt = 0; nt < 8; ++nt) {
            const bhalf8 bh = *(const bhalf8*)(wah + (nt * 16 + lr) * 128 + k0);
            const bhalf8 bl = *(const bhalf8*)(wal + (nt * 16 + lr) * 128 + k0);
            acc[nt] = __builtin_amdgcn_mfma_f32_16x16x32_bf16(zh, bh, acc[nt], 0, 0, 0);
            acc[nt] = __builtin_amdgcn_mfma_f32_16x16x32_bf16(zl, bh, acc[nt], 0, 0, 0);
            acc[nt] = __builtin_amdgcn_mfma_f32_16x16x32_bf16(zh, bl, acc[nt], 0, 0, 0);
        }
    }
    // write mid (relu) to LDS, per-wave transpose, XOR-swizzled
    char* hb = (char*)hbuf;
#pragma unroll
    for (int nt = 0; nt < 8; ++nt) {
#pragma unroll
        for (int j = 0; j < 4; ++j) {
            int rl = w * 16 + lg * 4 + j;
            int boff = (rl * 512 + (nt * 16 + lr) * 4) ^ ((rl & 7) << 4);
            *(float*)(hb + boff) = fmaxf(acc[nt][j], 0.f);
        }
    }
    __syncthreads();   // also orders lsum zeroing before epilogue atomics

    // ---- layer 2: out = mid @ Wb + Bb ----
#pragma unroll
    for (int nt = 0; nt < 8; ++nt) {
        float b = Bb[nt * 16 + lr];
        acc[nt][0] = b; acc[nt][1] = b; acc[nt][2] = b; acc[nt][3] = b;
    }
    const ushort_t* wbh = WB;
    const ushort_t* wbl = WB + 16384;
    {
        int rl = w * 16 + lr;
        int swz = (rl & 7) << 4;
        int rbase = rl * 512 + lg * 32;
#pragma unroll
        for (int ks = 0; ks < 4; ++ks) {
            int base = rbase + ks * 128;
            float4 f0 = *(const float4*)(hb + ((base) ^ swz));
            float4 f1 = *(const float4*)(hb + ((base + 16) ^ swz));
            bhalf8 zh, zl; split8(f0, f1, zh, zl);
            int k0 = ks * 32 + lg * 8;
#pragma unroll
            for (int nt = 0; nt < 8; ++nt) {
                const bhalf8 bh = *(const bhalf8*)(wbh + (nt * 16 + lr) * 128 + k0);
                const bhalf8 bl = *(const bhalf8*)(wbl + (nt * 16 + lr) * 128 + k0);
                acc[nt] = __builtin_amdgcn_mfma_f32_16x16x32_bf16(zh, bh, acc[nt], 0, 0, 0);
                acc[nt] = __builtin_amdgcn_mfma_f32_16x16x32_bf16(zl, bh, acc[nt], 0, 0, 0);
                acc[nt] = __builtin_amdgcn_mfma_f32_16x16x32_bf16(zh, bl, acc[nt], 0, 0, 0);
            }
        }
    }

    // ---- epilogue: store (+relu), BN stats ----
    if (active) {
#pragma unroll
        for (int nt = 0; nt < 8; ++nt) {
            float s = 0.f, q = 0.f;
#pragma unroll
            for (int j = 0; j < 4; ++j) {
                float v = acc[nt][j];
                if (RELU_OUT) v = fmaxf(v, 0.f);
                Out[(size_t)(rowBase + lg * 4 + j) * 128 + nt * 16 + lr] = v;
                if (STATS) { s += v; q += v * v; }
            }
            if (STATS) {
                s += __shfl_xor(s, 16); s += __shfl_xor(s, 32);
                q += __shfl_xor(q, 16); q += __shfl_xor(q, 32);
                if (l < 16) {
                    atomicAdd(&lsum[nt * 16 + l], s);
                    atomicAdd(&lsq[nt * 16 + l], q);
                }
            }
        }
    }
    if (STATS) {
        __syncthreads();
        if (t < 128) {
            unsafeAtomicAdd(&stats[t], lsum[t]);
            unsafeAtomicAdd(&stats[128 + t], lsq[t]);
        }
    }
}

extern "C" void kernel_launch(void* const* d_in, const int* in_sizes, int n_in,
                              void* d_out, int out_size, void* d_ws, size_t ws_size,
                              hipStream_t stream) {
    const float* x     = (const float*)d_in[0];
    const int*   ei    = (const int*)d_in[1];
    const float* w1a   = (const float*)d_in[2];
    const float* b1a   = (const float*)d_in[3];
    const float* w1b   = (const float*)d_in[4];
    const float* b1b   = (const float*)d_in[5];
    const float* gamma = (const float*)d_in[6];
    const float* beta  = (const float*)d_in[7];
    const float* w2a   = (const float*)d_in[8];
    const float* b2a   = (const float*)d_in[9];
    const float* w2b   = (const float*)d_in[10];
    const float* b2b   = (const float*)d_in[11];
    float* out = (float*)d_out;

    char*     ws    = (char*)d_ws;
    float*    stats = (float*)ws;                  // 256 floats
    int*      flag  = (int*)(ws + 1024);
    int*      H     = (int*)(ws + 4096);           // N ints
    int*      C     = (int*)(ws + 404096);         // N ints (scan -> ends)
    int*      ssrc  = (int*)(ws + 804096);         // E ints
    ushort_t* wbuf  = (ushort_t*)(ws + 0x700000);  // 4 x (hi+lo) bf16 weights
    float*    zbuf  = (float*)(ws + 0x800000);     // N*D floats (51.2 MB)

    const int aggBlocks = NNODES / 8;              // 12500
    const int mlpBlocks = (NNODES + 63) / 64;      // 1563

    // ---- build CSR once + weight prep ----
    k_setup<<<1, 256, 0, stream>>>(ei, stats, flag);
    k_zero<<<(NNODES + 1023) / 1024, 1024, 0, stream>>>(H);
    k_hist<<<2048, 256, 0, stream>>>(ei, flag, H);
    k_scan<<<1, 1024, 0, stream>>>(H, C);
    k_place<<<2048, 256, 0, stream>>>(ei, flag, C, ssrc);
    k_wprep<<<4, 256, 0, stream>>>(w1a, w1b, w2a, w2b, wbuf);
    // ---- conv1 ----
    k_agg<false><<<aggBlocks, 256, 0, stream>>>(x, zbuf, C, ssrc, nullptr, nullptr);
    k_mlp<true, true><<<mlpBlocks, 256, 0, stream>>>(
        zbuf, wbuf, wbuf + 32768, b1a, b1b, out, stats);
    // ---- BN params ----
    k_bn<<<1, 128, 0, stream>>>(stats, gamma, beta);
    // ---- conv2 (BN fused into aggregate) ----
    k_agg<true><<<aggBlocks, 256, 0, stream>>>(out, zbuf, C, ssrc, stats, stats + DIM);
    k_mlp<false, false><<<mlpBlocks, 256, 0, stream>>>(
        zbuf, wbuf + 65536, wbuf + 98304, b2a, b2b, out, nullptr);
}

// Round 4
// 569.963 us; speedup vs baseline: 10.7677x; 1.4250x over previous
//
#include <hip/hip_runtime.h>

#define NNODES 100000
#define NEDGES 1600000
#define DIM 128
#define BN_EPS 1e-5f
#define NBUCK 1024              // coarse buckets, dst>>7 -> 782 used
#define NB_USED ((NNODES + 127) / 128)   // 782

typedef unsigned int uint;
typedef unsigned short ushort_t;
using bhalf8  = __attribute__((ext_vector_type(8))) short;
using f32x4_t = __attribute__((ext_vector_type(4))) float;

// ---- edge access helper: flag=1 -> int64 layout, flag=0 -> int32 -----------
__device__ __forceinline__ int edge_src(const int* ei, int fl, int e) {
    return fl ? ei[2 * e] : ei[e];
}
__device__ __forceinline__ int edge_dst(const int* ei, int fl, int e) {
    return fl ? ei[2 * (NEDGES + e)] : ei[NEDGES + e];
}

// ---------------- setup: detect edge dtype + zero stats + zero bucket cnts --
__global__ __launch_bounds__(256) void k_setup(const int* __restrict__ ei,
                                               float* __restrict__ stats,
                                               int* __restrict__ flag,
                                               int* __restrict__ bcnt) {
    int t = threadIdx.x;
    stats[t] = 0.0f;  // sums[128] + sumsq[128]
    ((int4*)bcnt)[t] = make_int4(0, 0, 0, 0);
    if (t == 0) {
        int orr = 0;
        for (int i = 1; i < 128; i += 2) orr |= ei[i];
        *flag = (orr == 0) ? 1 : 0;
    }
}

// ---------------- pass 1: coarse bucket counts ------------------------------
__global__ __launch_bounds__(256) void k_bcount(const int* __restrict__ ei,
                                                const int* __restrict__ flag,
                                                int* __restrict__ bcnt) {
    __shared__ int h[NBUCK];
    int t = threadIdx.x;
    for (int i = t; i < NBUCK; i += 256) h[i] = 0;
    __syncthreads();
    int fl = *flag;
    int per = (NEDGES + gridDim.x - 1) / gridDim.x;
    int e0 = blockIdx.x * per;
    int e1 = min(e0 + per, NEDGES);
    for (int e = e0 + t; e < e1; e += 256)
        atomicAdd(&h[edge_dst(ei, fl, e) >> 7], 1);
    __syncthreads();
    for (int i = t; i < NBUCK; i += 256)
        if (h[i]) atomicAdd(&bcnt[i], h[i]);
}

// ---------------- pass 2: exscan of 1024 bucket counts ----------------------
__global__ __launch_bounds__(256) void k_bscan(const int* __restrict__ bcnt,
                                               int* __restrict__ bstart,
                                               int* __restrict__ bcur) {
    __shared__ int wtot[4];
    int t = threadIdx.x, lane = t & 63, w = t >> 6;
    int4 v = ((const int4*)bcnt)[t];
    int s = v.x + v.y + v.z + v.w;
    int sc = s;
#pragma unroll
    for (int d = 1; d < 64; d <<= 1) {
        int n = __shfl_up(sc, d, 64);
        if (lane >= d) sc += n;
    }
    if (lane == 63) wtot[w] = sc;
    __syncthreads();
    int woff = 0;
    for (int i = 0; i < w; ++i) woff += wtot[i];
    int excl = woff + sc - s;
    int o0 = excl, o1 = o0 + v.x, o2 = o1 + v.y, o3 = o2 + v.z;
    bstart[t * 4]     = o0;  bcur[t * 4]     = o0;
    bstart[t * 4 + 1] = o1;  bcur[t * 4 + 1] = o1;
    bstart[t * 4 + 2] = o2;  bcur[t * 4 + 2] = o2;
    bstart[t * 4 + 3] = o3;  bcur[t * 4 + 3] = o3;
    if (t == 255) bstart[NBUCK] = o3 + v.w;
}

// ---------------- pass 3: scatter (src,dst) pairs into coarse buckets -------
// Block-local histogram -> one global reservation per (block,bucket) ->
// contiguous writes within each bucket (write amp ~1x).
__global__ __launch_bounds__(256) void k_bpair(const int* __restrict__ ei,
                                               const int* __restrict__ flag,
                                               int* __restrict__ bcur,
                                               int2* __restrict__ pairs) {
    __shared__ int h[NBUCK];
    __shared__ int base[NBUCK];
    int t = threadIdx.x;
    for (int i = t; i < NBUCK; i += 256) h[i] = 0;
    __syncthreads();
    int fl = *flag;
    int per = (NEDGES + gridDim.x - 1) / gridDim.x;
    int e0 = blockIdx.x * per;
    int e1 = min(e0 + per, NEDGES);
    for (int e = e0 + t; e < e1; e += 256)
        atomicAdd(&h[edge_dst(ei, fl, e) >> 7], 1);
    __syncthreads();
    for (int i = t; i < NBUCK; i += 256) {
        int c = h[i];
        base[i] = c ? atomicAdd(&bcur[i], c) : 0;
    }
    __syncthreads();
    for (int i = t; i < NBUCK; i += 256) h[i] = 0;
    __syncthreads();
    for (int e = e0 + t; e < e1; e += 256) {
        int s = edge_src(ei, fl, e);
        int d = edge_dst(ei, fl, e);
        int b = d >> 7;
        int pos = atomicAdd(&h[b], 1);
        pairs[base[b] + pos] = make_int2(s, d);
    }
}

// ---------------- pass 4: per-bucket local sort -> ssrc + row ends ----------
__global__ __launch_bounds__(256) void k_bsort(const int2* __restrict__ pairs,
                                               const int* __restrict__ bstart,
                                               int* __restrict__ C,
                                               int* __restrict__ ssrc) {
    __shared__ int cnt[128];
    __shared__ int off[128];
    int b = blockIdx.x;
    int t = threadIdx.x, lane = t & 63, w = t >> 6;
    int s = bstart[b], e = bstart[b + 1];
    if (t < 128) cnt[t] = 0;
    __syncthreads();
    for (int i = s + t; i < e; i += 256)
        atomicAdd(&cnt[pairs[i].y & 127], 1);
    __syncthreads();
    if (w == 0) {   // wave-scan 128 bins
        int c0 = cnt[lane], c1 = cnt[64 + lane];
        int s0 = c0, s1 = c1;
#pragma unroll
        for (int d = 1; d < 64; d <<= 1) {
            int n0 = __shfl_up(s0, d, 64);
            int n1 = __shfl_up(s1, d, 64);
            if (lane >= d) { s0 += n0; s1 += n1; }
        }
        int tot0 = __shfl(s0, 63, 64);
        off[lane]      = s0 - c0;
        off[64 + lane] = tot0 + s1 - c1;
    }
    __syncthreads();
    // write per-row inclusive ends (coalesced)
    if (t < 128) {
        int row = b * 128 + t;
        if (row < NNODES) C[row] = s + off[t] + cnt[t];
    }
    __syncthreads();
    // place (off becomes cursor)
    for (int i = s + t; i < e; i += 256) {
        int2 p = pairs[i];
        int pos = atomicAdd(&off[p.y & 127], 1);
        ssrc[s + pos] = p.x;
    }
}

// ---------------- weight prep: fp32 [k][n] -> bf16 hi/lo transposed [n][k] --
__global__ __launch_bounds__(256) void k_wprep(const float* __restrict__ w0,
                                               const float* __restrict__ w1,
                                               const float* __restrict__ w2,
                                               const float* __restrict__ w3,
                                               ushort_t* __restrict__ ob) {
    const float* w = (blockIdx.x == 0) ? w0 : (blockIdx.x == 1) ? w1
                   : (blockIdx.x == 2) ? w2 : w3;
    ushort_t* oh = ob + (size_t)blockIdx.x * 32768;
    ushort_t* ol = oh + 16384;
    for (int i = threadIdx.x; i < 16384; i += 256) {
        int k = i >> 7, n = i & 127;
        float v = w[i];
        uint u = __float_as_uint(v);
        uint r = u + 0x7FFFu + ((u >> 16) & 1u);   // RN to bf16
        ushort_t h = (ushort_t)(r >> 16);
        float hf = __uint_as_float(((uint)h) << 16);
        float lo = v - hf;
        uint u2 = __float_as_uint(lo);
        uint r2 = u2 + 0x7FFFu + ((u2 >> 16) & 1u);
        ushort_t lb = (ushort_t)(r2 >> 16);
        oh[n * 128 + k] = h;
        ol[n * 128 + k] = lb;
    }
}

// ---------------- split 8 fp32 -> bf16 hi (trunc) + bf16 lo ------------------
__device__ __forceinline__ void split8(const float4& f0, const float4& f1,
                                       bhalf8& h, bhalf8& l) {
    uint u[8] = { __float_as_uint(f0.x), __float_as_uint(f0.y),
                  __float_as_uint(f0.z), __float_as_uint(f0.w),
                  __float_as_uint(f1.x), __float_as_uint(f1.y),
                  __float_as_uint(f1.z), __float_as_uint(f1.w) };
    float fv[8] = { f0.x, f0.y, f0.z, f0.w, f1.x, f1.y, f1.z, f1.w };
    uint lu[8];
#pragma unroll
    for (int i = 0; i < 8; ++i) {
        float hf = __uint_as_float(u[i] & 0xffff0000u);
        lu[i] = __float_as_uint(fv[i] - hf);
    }
    union { uint4 q; bhalf8 s; } H, L;
    H.q.x = __builtin_amdgcn_perm(u[1], u[0], 0x07060302u);
    H.q.y = __builtin_amdgcn_perm(u[3], u[2], 0x07060302u);
    H.q.z = __builtin_amdgcn_perm(u[5], u[4], 0x07060302u);
    H.q.w = __builtin_amdgcn_perm(u[7], u[6], 0x07060302u);
    L.q.x = __builtin_amdgcn_perm(lu[1], lu[0], 0x07060302u);
    L.q.y = __builtin_amdgcn_perm(lu[3], lu[2], 0x07060302u);
    L.q.z = __builtin_amdgcn_perm(lu[5], lu[4], 0x07060302u);
    L.q.w = __builtin_amdgcn_perm(lu[7], lu[6], 0x07060302u);
    h = H.s; l = L.s;
}

// ---------------- gather-aggregate: Z[i] = f(X[i]) + sum_j f(X[src_j]) ------
template <bool BN>
__global__ __launch_bounds__(256) void k_agg(const float* __restrict__ X,
                                             float* __restrict__ Z,
                                             const int* __restrict__ ends,
                                             const int* __restrict__ ssrc,
                                             const float* __restrict__ scale,
                                             const float* __restrict__ shift) {
    int t = threadIdx.x;
    int g = t >> 5;          // 0..7 row group
    int l = t & 31;
    int row = blockIdx.x * 8 + g;
    int c4 = l * 4;
    int start = (row == 0) ? 0 : ends[row - 1];
    int end = ends[row];

    float4 sc, sh;
    if (BN) {
        sc = *(const float4*)(scale + c4);
        sh = *(const float4*)(shift + c4);
    }
    float4 acc = *(const float4*)(X + (size_t)row * DIM + c4);
    if (BN) {
        acc.x = fmaf(acc.x, sc.x, sh.x);
        acc.y = fmaf(acc.y, sc.y, sh.y);
        acc.z = fmaf(acc.z, sc.z, sh.z);
        acc.w = fmaf(acc.w, sc.w, sh.w);
    }
    int e = start;
    for (; e + 3 < end; e += 4) {
        int s0 = ssrc[e], s1 = ssrc[e + 1], s2 = ssrc[e + 2], s3 = ssrc[e + 3];
        float4 v0 = *(const float4*)(X + (size_t)s0 * DIM + c4);
        float4 v1 = *(const float4*)(X + (size_t)s1 * DIM + c4);
        float4 v2 = *(const float4*)(X + (size_t)s2 * DIM + c4);
        float4 v3 = *(const float4*)(X + (size_t)s3 * DIM + c4);
        float4 u;
        u.x = (v0.x + v1.x) + (v2.x + v3.x);
        u.y = (v0.y + v1.y) + (v2.y + v3.y);
        u.z = (v0.z + v1.z) + (v2.z + v3.z);
        u.w = (v0.w + v1.w) + (v2.w + v3.w);
        if (BN) {
            acc.x = fmaf(u.x, sc.x, fmaf(4.0f, sh.x, acc.x));
            acc.y = fmaf(u.y, sc.y, fmaf(4.0f, sh.y, acc.y));
            acc.z = fmaf(u.z, sc.z, fmaf(4.0f, sh.z, acc.z));
            acc.w = fmaf(u.w, sc.w, fmaf(4.0f, sh.w, acc.w));
        } else {
            acc.x += u.x; acc.y += u.y; acc.z += u.z; acc.w += u.w;
        }
    }
    for (; e < end; ++e) {
        int s0 = ssrc[e];
        float4 v = *(const float4*)(X + (size_t)s0 * DIM + c4);
        if (BN) {
            acc.x = fmaf(v.x, sc.x, sh.x + acc.x);
            acc.y = fmaf(v.y, sc.y, sh.y + acc.y);
            acc.z = fmaf(v.z, sc.z, sh.z + acc.z);
            acc.w = fmaf(v.w, sc.w, sh.w + acc.w);
        } else {
            acc.x += v.x; acc.y += v.y; acc.z += v.z; acc.w += v.w;
        }
    }
    *(float4*)(Z + (size_t)row * DIM + c4) = acc;
}

// ---------------- BN finalize: scale/shift from sums ------------------------
__global__ void k_bn(float* stats, const float* __restrict__ gamma,
                     const float* __restrict__ beta) {
    int c = threadIdx.x;  // 128 threads
    float s  = stats[c];
    float sq = stats[128 + c];
    float mean = s / (float)NNODES;
    float var  = sq / (float)NNODES - mean * mean;
    float sc = gamma[c] * rsqrtf(var + BN_EPS);
    float sh = beta[c] - mean * sc;
    stats[c]       = sc;
    stats[128 + c] = sh;
}

// ---------------- fused 2-layer MLP via split-bf16 MFMA ---------------------
template <bool STATS, bool RELU_OUT>
__global__ __launch_bounds__(256) void k_mlp(const float* __restrict__ Z,
                                             const ushort_t* __restrict__ WA,
                                             const ushort_t* __restrict__ WB,
                                             const float* __restrict__ Ba,
                                             const float* __restrict__ Bb,
                                             float* __restrict__ Out,
                                             float* __restrict__ stats) {
    __shared__ float hbuf[64 * 128];   // mid activations, XOR-swizzled
    __shared__ float lsum[128], lsq[128];

    int t = threadIdx.x;
    int w = t >> 6, l = t & 63;
    int lr = l & 15;
    int lg = l >> 4;
    if (STATS && t < 128) { lsum[t] = 0.f; lsq[t] = 0.f; }

    int rowBase = blockIdx.x * 64 + w * 16;
    bool active = rowBase < NNODES;

    // ---- layer 1: mid = relu(Z @ Wa + Ba) ----
    f32x4_t acc[8];
#pragma unroll
    for (int nt = 0; nt < 8; ++nt) {
        float b = Ba[nt * 16 + lr];
        acc[nt][0] = b; acc[nt][1] = b; acc[nt][2] = b; acc[nt][3] = b;
    }
    const ushort_t* wah = WA;
    const ushort_t* wal = WA + 16384;
    int zrow = active ? (rowBase + lr) : 0;
    const float* zp = Z + (size_t)zrow * 128 + lg * 8;
#pragma unroll
    for (int ks = 0; ks < 4; ++ks) {
        float4 f0 = *(const float4*)(zp + ks * 32);
        float4 f1 = *(const float4*)(zp + ks * 32 + 4);
        bhalf8 zh, zl; split8(f0, f1, zh, zl);
        int k0 = ks * 32 + lg * 8;
#pragma unroll
        for (int nt = 0; nt < 8; ++nt) {
            const bhalf8 bh = *(const bhalf8*)(wah + (nt * 16 + lr) * 128 + k0);
            const bhalf8 bl = *(const bhalf8*)(wal + (nt * 16 + lr) * 128 + k0);
            acc[nt] = __builtin_amdgcn_mfma_f32_16x16x32_bf16(zh, bh, acc[nt], 0, 0, 0);
            acc[nt] = __builtin_amdgcn_mfma_f32_16x16x32_bf16(zl, bh, acc[nt], 0, 0, 0);
            acc[nt] = __builtin_amdgcn_mfma_f32_16x16x32_bf16(zh, bl, acc[nt], 0, 0, 0);
        }
    }
    char* hb = (char*)hbuf;
#pragma unroll
    for (int nt = 0; nt < 8; ++nt) {
#pragma unroll
        for (int j = 0; j < 4; ++j) {
            int rl = w * 16 + lg * 4 + j;
            int boff = (rl * 512 + (nt * 16 + lr) * 4) ^ ((rl & 7) << 4);
            *(float*)(hb + boff) = fmaxf(acc[nt][j], 0.f);
        }
    }
    __syncthreads();

    // ---- layer 2: out = mid @ Wb + Bb ----
#pragma unroll
    for (int nt = 0; nt < 8; ++nt) {
        float b = Bb[nt * 16 + lr];
        acc[nt][0] = b; acc[nt][1] = b; acc[nt][2] = b; acc[nt][3] = b;
    }
    const ushort_t* wbh = WB;
    const ushort_t* wbl = WB + 16384;
    {
        int rl = w * 16 + lr;
        int swz = (rl & 7) << 4;
        int rbase = rl * 512 + lg * 32;
#pragma unroll
        for (int ks = 0; ks < 4; ++ks) {
            int base = rbase + ks * 128;
            float4 f0 = *(const float4*)(hb + ((base) ^ swz));
            float4 f1 = *(const float4*)(hb + ((base + 16) ^ swz));
            bhalf8 zh, zl; split8(f0, f1, zh, zl);
            int k0 = ks * 32 + lg * 8;
#pragma unroll
            for (int nt = 0; nt < 8; ++nt) {
                const bhalf8 bh = *(const bhalf8*)(wbh + (nt * 16 + lr) * 128 + k0);
                const bhalf8 bl = *(const bhalf8*)(wbl + (nt * 16 + lr) * 128 + k0);
                acc[nt] = __builtin_amdgcn_mfma_f32_16x16x32_bf16(zh, bh, acc[nt], 0, 0, 0);
                acc[nt] = __builtin_amdgcn_mfma_f32_16x16x32_bf16(zl, bh, acc[nt], 0, 0, 0);
                acc[nt] = __builtin_amdgcn_mfma_f32_16x16x32_bf16(zh, bl, acc[nt], 0, 0, 0);
            }
        }
    }

    // ---- epilogue: store (+relu), BN stats ----
    if (active) {
#pragma unroll
        for (int nt = 0; nt < 8; ++nt) {
            float s = 0.f, q = 0.f;
#pragma unroll
            for (int j = 0; j < 4; ++j) {
                float v = acc[nt][j];
                if (RELU_OUT) v = fmaxf(v, 0.f);
                Out[(size_t)(rowBase + lg * 4 + j) * 128 + nt * 16 + lr] = v;
                if (STATS) { s += v; q += v * v; }
            }
            if (STATS) {
                s += __shfl_xor(s, 16); s += __shfl_xor(s, 32);
                q += __shfl_xor(q, 16); q += __shfl_xor(q, 32);
                if (l < 16) {
                    atomicAdd(&lsum[nt * 16 + l], s);
                    atomicAdd(&lsq[nt * 16 + l], q);
                }
            }
        }
    }
    if (STATS) {
        __syncthreads();
        if (t < 128) {
            unsafeAtomicAdd(&stats[t], lsum[t]);
            unsafeAtomicAdd(&stats[128 + t], lsq[t]);
        }
    }
}

extern "C" void kernel_launch(void* const* d_in, const int* in_sizes, int n_in,
                              void* d_out, int out_size, void* d_ws, size_t ws_size,
                              hipStream_t stream) {
    const float* x     = (const float*)d_in[0];
    const int*   ei    = (const int*)d_in[1];
    const float* w1a   = (const float*)d_in[2];
    const float* b1a   = (const float*)d_in[3];
    const float* w1b   = (const float*)d_in[4];
    const float* b1b   = (const float*)d_in[5];
    const float* gamma = (const float*)d_in[6];
    const float* beta  = (const float*)d_in[7];
    const float* w2a   = (const float*)d_in[8];
    const float* b2a   = (const float*)d_in[9];
    const float* w2b   = (const float*)d_in[10];
    const float* b2b   = (const float*)d_in[11];
    float* out = (float*)d_out;

    char*     ws     = (char*)d_ws;
    float*    stats  = (float*)ws;                  // 256 floats
    int*      flag   = (int*)(ws + 1024);
    int*      bcnt   = (int*)(ws + 4096);           // 1024 ints
    int*      bstart = (int*)(ws + 8192);           // 1025 ints
    int*      bcur   = (int*)(ws + 16384);          // 1024 ints
    int*      C      = (int*)(ws + 404096);         // N ints (row ends)
    int*      ssrc   = (int*)(ws + 804096);         // E ints
    ushort_t* wbuf   = (ushort_t*)(ws + 0x700000);  // 4 x (hi+lo) bf16 weights
    float*    zbuf   = (float*)(ws + 0x800000);     // N*D floats (51.2 MB)
    int2*     pairs  = (int2*)(ws + 0x800000);      // 12.8 MB, dead before zbuf use

    const int aggBlocks = NNODES / 8;               // 12500
    const int mlpBlocks = (NNODES + 63) / 64;       // 1563

    // ---- build CSR (bucketed counting sort) + weight prep ----
    k_setup<<<1, 256, 0, stream>>>(ei, stats, flag, bcnt);
    k_bcount<<<256, 256, 0, stream>>>(ei, flag, bcnt);
    k_bscan<<<1, 256, 0, stream>>>(bcnt, bstart, bcur);
    k_bpair<<<256, 256, 0, stream>>>(ei, flag, bcur, pairs);
    k_bsort<<<NB_USED, 256, 0, stream>>>(pairs, bstart, C, ssrc);
    k_wprep<<<4, 256, 0, stream>>>(w1a, w1b, w2a, w2b, wbuf);
    // ---- conv1 ----
    k_agg<false><<<aggBlocks, 256, 0, stream>>>(x, zbuf, C, ssrc, nullptr, nullptr);
    k_mlp<true, true><<<mlpBlocks, 256, 0, stream>>>(
        zbuf, wbuf, wbuf + 32768, b1a, b1b, out, stats);
    // ---- BN params ----
    k_bn<<<1, 128, 0, stream>>>(stats, gamma, beta);
    // ---- conv2 (BN fused into aggregate) ----
    k_agg<true><<<aggBlocks, 256, 0, stream>>>(out, zbuf, C, ssrc, stats, stats + DIM);
    k_mlp<false, false><<<mlpBlocks, 256, 0, stream>>>(
        zbuf, wbuf + 65536, wbuf + 98304, b2a, b2b, out, nullptr);
}

// Round 5
// 489.943 us; speedup vs baseline: 12.5263x; 1.1633x over previous
//
#include <hip/hip_runtime.h>

#define NNODES 100000
#define NEDGES 1600000
#define DIM 128
#define BN_EPS 1e-5f
#define NBUCK 1024              // coarse buckets, dst>>7 -> 782 used
#define NB_USED ((NNODES + 127) / 128)   // 782

typedef unsigned int uint;
typedef unsigned short ushort_t;
using bhalf8  = __attribute__((ext_vector_type(8))) short;
using u16x8   = __attribute__((ext_vector_type(8))) unsigned short;
using f32x4_t = __attribute__((ext_vector_type(4))) float;

__device__ __forceinline__ float bf2f(uint u16) {
    return __uint_as_float(u16 << 16);
}
__device__ __forceinline__ uint pack2_bf16rn(float a, float b) {
    uint ua = __float_as_uint(a); ua += 0x7FFFu + ((ua >> 16) & 1u);
    uint ub = __float_as_uint(b); ub += 0x7FFFu + ((ub >> 16) & 1u);
    return __builtin_amdgcn_perm(ub, ua, 0x07060302u);  // {a.hi16, b.hi16}
}

// ---- edge access helper: flag=1 -> int64 layout, flag=0 -> int32 -----------
__device__ __forceinline__ int edge_src(const int* ei, int fl, int e) {
    return fl ? ei[2 * e] : ei[e];
}
__device__ __forceinline__ int edge_dst(const int* ei, int fl, int e) {
    return fl ? ei[2 * (NEDGES + e)] : ei[NEDGES + e];
}

// ---------------- setup: detect edge dtype + zero stats + zero bucket cnts --
__global__ __launch_bounds__(256) void k_setup(const int* __restrict__ ei,
                                               float* __restrict__ stats,
                                               int* __restrict__ flag,
                                               int* __restrict__ bcnt) {
    int t = threadIdx.x;
    stats[t] = 0.0f;  // sums[128] + sumsq[128]
    ((int4*)bcnt)[t] = make_int4(0, 0, 0, 0);
    if (t == 0) {
        int orr = 0;
        for (int i = 1; i < 128; i += 2) orr |= ei[i];
        *flag = (orr == 0) ? 1 : 0;
    }
}

// ---------------- pass 1: coarse bucket counts ------------------------------
__global__ __launch_bounds__(256) void k_bcount(const int* __restrict__ ei,
                                                const int* __restrict__ flag,
                                                int* __restrict__ bcnt) {
    __shared__ int h[NBUCK];
    int t = threadIdx.x;
    for (int i = t; i < NBUCK; i += 256) h[i] = 0;
    __syncthreads();
    int fl = *flag;
    int per = (NEDGES + gridDim.x - 1) / gridDim.x;
    int e0 = blockIdx.x * per;
    int e1 = min(e0 + per, NEDGES);
    for (int e = e0 + t; e < e1; e += 256)
        atomicAdd(&h[edge_dst(ei, fl, e) >> 7], 1);
    __syncthreads();
    for (int i = t; i < NBUCK; i += 256)
        if (h[i]) atomicAdd(&bcnt[i], h[i]);
}

// ---------------- pass 2: exscan of 1024 bucket counts ----------------------
__global__ __launch_bounds__(256) void k_bscan(const int* __restrict__ bcnt,
                                               int* __restrict__ bstart,
                                               int* __restrict__ bcur) {
    __shared__ int wtot[4];
    int t = threadIdx.x, lane = t & 63, w = t >> 6;
    int4 v = ((const int4*)bcnt)[t];
    int s = v.x + v.y + v.z + v.w;
    int sc = s;
#pragma unroll
    for (int d = 1; d < 64; d <<= 1) {
        int n = __shfl_up(sc, d, 64);
        if (lane >= d) sc += n;
    }
    if (lane == 63) wtot[w] = sc;
    __syncthreads();
    int woff = 0;
    for (int i = 0; i < w; ++i) woff += wtot[i];
    int excl = woff + sc - s;
    int o0 = excl, o1 = o0 + v.x, o2 = o1 + v.y, o3 = o2 + v.z;
    bstart[t * 4]     = o0;  bcur[t * 4]     = o0;
    bstart[t * 4 + 1] = o1;  bcur[t * 4 + 1] = o1;
    bstart[t * 4 + 2] = o2;  bcur[t * 4 + 2] = o2;
    bstart[t * 4 + 3] = o3;  bcur[t * 4 + 3] = o3;
    if (t == 255) bstart[NBUCK] = o3 + v.w;
}

// ---------------- pass 3: scatter packed (src<<7|dst&127) into buckets ------
__global__ __launch_bounds__(256) void k_bpair(const int* __restrict__ ei,
                                               const int* __restrict__ flag,
                                               int* __restrict__ bcur,
                                               int* __restrict__ pairs) {
    __shared__ int h[NBUCK];
    __shared__ int base[NBUCK];
    int t = threadIdx.x;
    for (int i = t; i < NBUCK; i += 256) h[i] = 0;
    __syncthreads();
    int fl = *flag;
    int per = (NEDGES + gridDim.x - 1) / gridDim.x;
    int e0 = blockIdx.x * per;
    int e1 = min(e0 + per, NEDGES);
    for (int e = e0 + t; e < e1; e += 256)
        atomicAdd(&h[edge_dst(ei, fl, e) >> 7], 1);
    __syncthreads();
    for (int i = t; i < NBUCK; i += 256) {
        int c = h[i];
        base[i] = c ? atomicAdd(&bcur[i], c) : 0;
    }
    __syncthreads();
    for (int i = t; i < NBUCK; i += 256) h[i] = 0;
    __syncthreads();
    for (int e = e0 + t; e < e1; e += 256) {
        int s = edge_src(ei, fl, e);
        int d = edge_dst(ei, fl, e);
        int b = d >> 7;
        int pos = atomicAdd(&h[b], 1);
        pairs[base[b] + pos] = (s << 7) | (d & 127);
    }
}

// ---------------- pass 4: per-bucket local sort -> ssrc + row ends ----------
__global__ __launch_bounds__(256) void k_bsort(const int* __restrict__ pairs,
                                               const int* __restrict__ bstart,
                                               int* __restrict__ C,
                                               int* __restrict__ ssrc) {
    __shared__ int cnt[128];
    __shared__ int off[128];
    int b = blockIdx.x;
    int t = threadIdx.x, lane = t & 63, w = t >> 6;
    int s = bstart[b], e = bstart[b + 1];
    if (t < 128) cnt[t] = 0;
    __syncthreads();
    for (int i = s + t; i < e; i += 256)
        atomicAdd(&cnt[pairs[i] & 127], 1);
    __syncthreads();
    if (w == 0) {   // wave-scan 128 bins
        int c0 = cnt[lane], c1 = cnt[64 + lane];
        int s0 = c0, s1 = c1;
#pragma unroll
        for (int d = 1; d < 64; d <<= 1) {
            int n0 = __shfl_up(s0, d, 64);
            int n1 = __shfl_up(s1, d, 64);
            if (lane >= d) { s0 += n0; s1 += n1; }
        }
        int tot0 = __shfl(s0, 63, 64);
        off[lane]      = s0 - c0;
        off[64 + lane] = tot0 + s1 - c1;
    }
    __syncthreads();
    if (t < 128) {
        int row = b * 128 + t;
        if (row < NNODES) C[row] = s + off[t] + cnt[t];
    }
    __syncthreads();
    for (int i = s + t; i < e; i += 256) {
        int p = pairs[i];
        int pos = atomicAdd(&off[p & 127], 1);
        ssrc[s + pos] = p >> 7;
    }
}

// ---------------- weight prep: fp32 [k][n] -> bf16 hi/lo transposed [n][k] --
__global__ __launch_bounds__(256) void k_wprep(const float* __restrict__ w0,
                                               const float* __restrict__ w1,
                                               const float* __restrict__ w2,
                                               const float* __restrict__ w3,
                                               ushort_t* __restrict__ ob) {
    const float* w = (blockIdx.x == 0) ? w0 : (blockIdx.x == 1) ? w1
                   : (blockIdx.x == 2) ? w2 : w3;
    ushort_t* oh = ob + (size_t)blockIdx.x * 32768;
    ushort_t* ol = oh + 16384;
    for (int i = threadIdx.x; i < 16384; i += 256) {
        int k = i >> 7, n = i & 127;
        float v = w[i];
        uint u = __float_as_uint(v);
        uint r = u + 0x7FFFu + ((u >> 16) & 1u);   // RN to bf16
        ushort_t h = (ushort_t)(r >> 16);
        float hf = __uint_as_float(((uint)h) << 16);
        float lo = v - hf;
        uint u2 = __float_as_uint(lo);
        uint r2 = u2 + 0x7FFFu + ((u2 >> 16) & 1u);
        ushort_t lb = (ushort_t)(r2 >> 16);
        oh[n * 128 + k] = h;
        ol[n * 128 + k] = lb;
    }
}

// ---------------- x (fp32) -> xb (bf16 RN) ----------------------------------
__global__ __launch_bounds__(256) void k_xconv(const float* __restrict__ X,
                                               ushort_t* __restrict__ Xb) {
    size_t i = ((size_t)blockIdx.x * 256 + threadIdx.x) * 8;
    float4 a = *(const float4*)(X + i);
    float4 b = *(const float4*)(X + i + 4);
    union { uint4 q; u16x8 v; } o;
    o.q.x = pack2_bf16rn(a.x, a.y);
    o.q.y = pack2_bf16rn(a.z, a.w);
    o.q.z = pack2_bf16rn(b.x, b.y);
    o.q.w = pack2_bf16rn(b.z, b.w);
    *(u16x8*)(Xb + i) = o.v;
}

// ---------------- split 8 fp32 -> bf16 hi (trunc) + bf16 lo ------------------
__device__ __forceinline__ void split8(const float4& f0, const float4& f1,
                                       bhalf8& h, bhalf8& l) {
    uint u[8] = { __float_as_uint(f0.x), __float_as_uint(f0.y),
                  __float_as_uint(f0.z), __float_as_uint(f0.w),
                  __float_as_uint(f1.x), __float_as_uint(f1.y),
                  __float_as_uint(f1.z), __float_as_uint(f1.w) };
    float fv[8] = { f0.x, f0.y, f0.z, f0.w, f1.x, f1.y, f1.z, f1.w };
    uint lu[8];
#pragma unroll
    for (int i = 0; i < 8; ++i) {
        float hf = __uint_as_float(u[i] & 0xffff0000u);
        lu[i] = __float_as_uint(fv[i] - hf);
    }
    union { uint4 q; bhalf8 s; } H, L;
    H.q.x = __builtin_amdgcn_perm(u[1], u[0], 0x07060302u);
    H.q.y = __builtin_amdgcn_perm(u[3], u[2], 0x07060302u);
    H.q.z = __builtin_amdgcn_perm(u[5], u[4], 0x07060302u);
    H.q.w = __builtin_amdgcn_perm(u[7], u[6], 0x07060302u);
    L.q.x = __builtin_amdgcn_perm(lu[1], lu[0], 0x07060302u);
    L.q.y = __builtin_amdgcn_perm(lu[3], lu[2], 0x07060302u);
    L.q.z = __builtin_amdgcn_perm(lu[5], lu[4], 0x07060302u);
    L.q.w = __builtin_amdgcn_perm(lu[7], lu[6], 0x07060302u);
    h = H.s; l = L.s;
}

// ---------------- gather-aggregate (bf16 neighbors) -------------------------
// Z[i] = g(self_i + sum_j hb[src_j]); g = BN affine applied once at the end.
// 16 lanes per row, 8 cols/lane, 16 rows/block.
template <bool BN, bool SELF_F32>
__global__ __launch_bounds__(256) void k_agg(const ushort_t* __restrict__ Xb,
                                             const float* __restrict__ Xf,
                                             float* __restrict__ Z,
                                             const int* __restrict__ ends,
                                             const int* __restrict__ ssrc,
                                             const float* __restrict__ scale,
                                             const float* __restrict__ shift) {
    int t = threadIdx.x;
    int g = t >> 4;          // 0..15 row in block
    int l = t & 15;
    int row = blockIdx.x * 16 + g;
    int c8 = l * 8;
    int start = (row == 0) ? 0 : ends[row - 1];
    int end = ends[row];

    float acc[8];
    if (SELF_F32) {
        float4 a0 = *(const float4*)(Xf + (size_t)row * DIM + c8);
        float4 a1 = *(const float4*)(Xf + (size_t)row * DIM + c8 + 4);
        acc[0] = a0.x; acc[1] = a0.y; acc[2] = a0.z; acc[3] = a0.w;
        acc[4] = a1.x; acc[5] = a1.y; acc[6] = a1.z; acc[7] = a1.w;
    } else {
        union { u16x8 v; uint u[4]; } sv;
        sv.v = *(const u16x8*)(Xb + (size_t)row * DIM + c8);
#pragma unroll
        for (int i = 0; i < 4; ++i) {
            acc[2 * i]     = bf2f(sv.u[i] << 16 >> 16);   // low half
            acc[2 * i + 1] = __uint_as_float(sv.u[i] & 0xffff0000u);
        }
    }

    int e = start;
    for (; e + 7 < end; e += 8) {
        union { u16x8 v; uint u[4]; } nv[8];
#pragma unroll
        for (int i = 0; i < 8; ++i) {
            int s0 = ssrc[e + i];
            nv[i].v = *(const u16x8*)(Xb + (size_t)s0 * DIM + c8);
        }
#pragma unroll
        for (int i = 0; i < 8; ++i) {
#pragma unroll
            for (int j = 0; j < 4; ++j) {
                acc[2 * j]     += bf2f(nv[i].u[j] & 0xffffu);
                acc[2 * j + 1] += __uint_as_float(nv[i].u[j] & 0xffff0000u);
            }
        }
    }
    for (; e < end; ++e) {
        int s0 = ssrc[e];
        union { u16x8 v; uint u[4]; } nv;
        nv.v = *(const u16x8*)(Xb + (size_t)s0 * DIM + c8);
#pragma unroll
        for (int j = 0; j < 4; ++j) {
            acc[2 * j]     += bf2f(nv.u[j] & 0xffffu);
            acc[2 * j + 1] += __uint_as_float(nv.u[j] & 0xffff0000u);
        }
    }

    if (BN) {
        float4 sc0 = *(const float4*)(scale + c8);
        float4 sc1 = *(const float4*)(scale + c8 + 4);
        float4 sh0 = *(const float4*)(shift + c8);
        float4 sh1 = *(const float4*)(shift + c8 + 4);
        float cnt = (float)(end - start + 1);
        acc[0] = fmaf(acc[0], sc0.x, cnt * sh0.x);
        acc[1] = fmaf(acc[1], sc0.y, cnt * sh0.y);
        acc[2] = fmaf(acc[2], sc0.z, cnt * sh0.z);
        acc[3] = fmaf(acc[3], sc0.w, cnt * sh0.w);
        acc[4] = fmaf(acc[4], sc1.x, cnt * sh1.x);
        acc[5] = fmaf(acc[5], sc1.y, cnt * sh1.y);
        acc[6] = fmaf(acc[6], sc1.z, cnt * sh1.z);
        acc[7] = fmaf(acc[7], sc1.w, cnt * sh1.w);
    }
    float* zp = Z + (size_t)row * DIM + c8;
    *(float4*)zp       = make_float4(acc[0], acc[1], acc[2], acc[3]);
    *(float4*)(zp + 4) = make_float4(acc[4], acc[5], acc[6], acc[7]);
}

// ---------------- BN finalize: scale/shift from sums ------------------------
__global__ void k_bn(float* stats, const float* __restrict__ gamma,
                     const float* __restrict__ beta) {
    int c = threadIdx.x;  // 128 threads
    float s  = stats[c];
    float sq = stats[128 + c];
    float mean = s / (float)NNODES;
    float var  = sq / (float)NNODES - mean * mean;
    float sc = gamma[c] * rsqrtf(var + BN_EPS);
    float sh = beta[c] - mean * sc;
    stats[c]       = sc;
    stats[128 + c] = sh;
}

// ---------------- fused 2-layer MLP via split-bf16 MFMA ---------------------
// CONV1: out = bf16(relu(...)) to OutB + BN stats. else: fp32 to OutF.
template <bool CONV1>
__global__ __launch_bounds__(256, 4) void k_mlp(const float* __restrict__ Z,
                                                const ushort_t* __restrict__ WA,
                                                const ushort_t* __restrict__ WB,
                                                const float* __restrict__ Ba,
                                                const float* __restrict__ Bb,
                                                float* __restrict__ OutF,
                                                ushort_t* __restrict__ OutB,
                                                float* __restrict__ stats) {
    __shared__ float hbuf[64 * 128];   // mid, then output staging (swizzled)
    __shared__ float lsum[128], lsq[128];
    char* hb = (char*)hbuf;

    int t = threadIdx.x;
    int w = t >> 6, l = t & 63;
    int lr = l & 15;
    int lg = l >> 4;
    if (CONV1 && t < 128) { lsum[t] = 0.f; lsq[t] = 0.f; }

    int rowBase = blockIdx.x * 64 + w * 16;
    bool active = rowBase < NNODES;

    // ---- layer 1: mid = relu(Z @ Wa + Ba) ----
    int zrow = active ? (rowBase + lr) : 0;
    const float* zp = Z + (size_t)zrow * 128 + lg * 8;
    float4 zf[8];
#pragma unroll
    for (int ks = 0; ks < 4; ++ks) {
        zf[2 * ks]     = *(const float4*)(zp + ks * 32);
        zf[2 * ks + 1] = *(const float4*)(zp + ks * 32 + 4);
    }
    bhalf8 zh[4], zl[4];
#pragma unroll
    for (int ks = 0; ks < 4; ++ks) split8(zf[2 * ks], zf[2 * ks + 1], zh[ks], zl[ks]);

    f32x4_t acc[8];
#pragma unroll
    for (int nt = 0; nt < 8; ++nt) {
        float b = Ba[nt * 16 + lr];
        acc[nt][0] = b; acc[nt][1] = b; acc[nt][2] = b; acc[nt][3] = b;
    }
    const ushort_t* wah = WA;
    const ushort_t* wal = WA + 16384;
#pragma unroll
    for (int ks = 0; ks < 4; ++ks) {
        int k0 = ks * 32 + lg * 8;
#pragma unroll
        for (int nt = 0; nt < 8; ++nt) {
            const bhalf8 bh = *(const bhalf8*)(wah + (nt * 16 + lr) * 128 + k0);
            const bhalf8 bl = *(const bhalf8*)(wal + (nt * 16 + lr) * 128 + k0);
            acc[nt] = __builtin_amdgcn_mfma_f32_16x16x32_bf16(zh[ks], bh, acc[nt], 0, 0, 0);
            acc[nt] = __builtin_amdgcn_mfma_f32_16x16x32_bf16(zl[ks], bh, acc[nt], 0, 0, 0);
            acc[nt] = __builtin_amdgcn_mfma_f32_16x16x32_bf16(zh[ks], bl, acc[nt], 0, 0, 0);
        }
    }
#pragma unroll
    for (int nt = 0; nt < 8; ++nt) {
#pragma unroll
        for (int j = 0; j < 4; ++j) {
            int rl = w * 16 + lg * 4 + j;
            int boff = (rl * 512 + (nt * 16 + lr) * 4) ^ ((rl & 7) << 4);
            *(float*)(hb + boff) = fmaxf(acc[nt][j], 0.f);
        }
    }
    __syncthreads();

    // ---- layer 2: out = mid @ Wb + Bb ----
    {
        int rl = w * 16 + lr;
        int swz = (rl & 7) << 4;
        int rbase = rl * 512 + lg * 32;
        float4 mf[8];
#pragma unroll
        for (int ks = 0; ks < 4; ++ks) {
            mf[2 * ks]     = *(const float4*)(hb + ((rbase + ks * 128) ^ swz));
            mf[2 * ks + 1] = *(const float4*)(hb + ((rbase + ks * 128 + 16) ^ swz));
        }
#pragma unroll
        for (int ks = 0; ks < 4; ++ks) split8(mf[2 * ks], mf[2 * ks + 1], zh[ks], zl[ks]);
    }
#pragma unroll
    for (int nt = 0; nt < 8; ++nt) {
        float b = Bb[nt * 16 + lr];
        acc[nt][0] = b; acc[nt][1] = b; acc[nt][2] = b; acc[nt][3] = b;
    }
    const ushort_t* wbh = WB;
    const ushort_t* wbl = WB + 16384;
#pragma unroll
    for (int ks = 0; ks < 4; ++ks) {
        int k0 = ks * 32 + lg * 8;
#pragma unroll
        for (int nt = 0; nt < 8; ++nt) {
            const bhalf8 bh = *(const bhalf8*)(wbh + (nt * 16 + lr) * 128 + k0);
            const bhalf8 bl = *(const bhalf8*)(wbl + (nt * 16 + lr) * 128 + k0);
            acc[nt] = __builtin_amdgcn_mfma_f32_16x16x32_bf16(zh[ks], bh, acc[nt], 0, 0, 0);
            acc[nt] = __builtin_amdgcn_mfma_f32_16x16x32_bf16(zl[ks], bh, acc[nt], 0, 0, 0);
            acc[nt] = __builtin_amdgcn_mfma_f32_16x16x32_bf16(zh[ks], bl, acc[nt], 0, 0, 0);
        }
    }

    // ---- epilogue: relu + stats (CONV1), stage via LDS, coalesced store ----
    if (CONV1 && active) {
#pragma unroll
        for (int nt = 0; nt < 8; ++nt) {
            float s = 0.f, q = 0.f;
#pragma unroll
            for (int j = 0; j < 4; ++j) {
                float v = fmaxf(acc[nt][j], 0.f);
                acc[nt][j] = v;
                s += v; q += v * v;
            }
            s += __shfl_xor(s, 16); s += __shfl_xor(s, 32);
            q += __shfl_xor(q, 16); q += __shfl_xor(q, 32);
            if (l < 16) {
                atomicAdd(&lsum[nt * 16 + l], s);
                atomicAdd(&lsq[nt * 16 + l], q);
            }
        }
    }
    __syncthreads();   // everyone done reading mid from hbuf
#pragma unroll
    for (int nt = 0; nt < 8; ++nt) {
#pragma unroll
        for (int j = 0; j < 4; ++j) {
            int rl = w * 16 + lg * 4 + j;
            int boff = (rl * 512 + (nt * 16 + lr) * 4) ^ ((rl & 7) << 4);
            *(float*)(hb + boff) = acc[nt][j];
        }
    }
    if (CONV1) {
        __syncthreads();
        if (t < 128) {
            unsafeAtomicAdd(&stats[t], lsum[t]);
            unsafeAtomicAdd(&stats[128 + t], lsq[t]);
        }
    } else {
        __syncthreads();
    }
    // readback: 4 threads per row, 128 B each, coalesced global stores
    {
        int r2 = t >> 2;
        int row = blockIdx.x * 64 + r2;
        if (row < NNODES) {
            int sw2 = (r2 & 7) << 4;
            int ch0 = (t & 3) * 8;
            if (CONV1) {
#pragma unroll
                for (int c = 0; c < 8; c += 2) {
                    float4 v0 = *(const float4*)(hb + ((r2 * 512 + (ch0 + c) * 16) ^ sw2));
                    float4 v1 = *(const float4*)(hb + ((r2 * 512 + (ch0 + c + 1) * 16) ^ sw2));
                    union { uint4 q; u16x8 v; } o;
                    o.q.x = pack2_bf16rn(v0.x, v0.y);
                    o.q.y = pack2_bf16rn(v0.z, v0.w);
                    o.q.z = pack2_bf16rn(v1.x, v1.y);
                    o.q.w = pack2_bf16rn(v1.z, v1.w);
                    *(u16x8*)(OutB + (size_t)row * 128 + (ch0 + c) * 4) = o.v;
                }
            } else {
#pragma unroll
                for (int c = 0; c < 8; ++c) {
                    float4 v = *(const float4*)(hb + ((r2 * 512 + (ch0 + c) * 16) ^ sw2));
                    *(float4*)(OutF + (size_t)row * 128 + (ch0 + c) * 4) = v;
                }
            }
        }
    }
}

extern "C" void kernel_launch(void* const* d_in, const int* in_sizes, int n_in,
                              void* d_out, int out_size, void* d_ws, size_t ws_size,
                              hipStream_t stream) {
    const float* x     = (const float*)d_in[0];
    const int*   ei    = (const int*)d_in[1];
    const float* w1a   = (const float*)d_in[2];
    const float* b1a   = (const float*)d_in[3];
    const float* w1b   = (const float*)d_in[4];
    const float* b1b   = (const float*)d_in[5];
    const float* gamma = (const float*)d_in[6];
    const float* beta  = (const float*)d_in[7];
    const float* w2a   = (const float*)d_in[8];
    const float* b2a   = (const float*)d_in[9];
    const float* w2b   = (const float*)d_in[10];
    const float* b2b   = (const float*)d_in[11];
    float* out = (float*)d_out;

    char*     ws     = (char*)d_ws;
    float*    stats  = (float*)ws;                  // 256 floats
    int*      flag   = (int*)(ws + 1024);
    int*      bcnt   = (int*)(ws + 4096);           // 1024 ints
    int*      bstart = (int*)(ws + 8192);           // 1025 ints
    int*      bcur   = (int*)(ws + 16384);          // 1024 ints
    int*      C      = (int*)(ws + 404096);         // N ints (row ends)
    int*      ssrc   = (int*)(ws + 804096);         // E ints
    ushort_t* wbuf   = (ushort_t*)(ws + 0x700000);  // 4 x (hi+lo) bf16 weights
    float*    zbuf   = (float*)(ws + 0x800000);     // N*D floats (51.2 MB)
    int*      pairs  = (int*)(ws + 0x800000);       // 6.4 MB, dead before zbuf use

    // bf16 scratch lives inside d_out (fully overwritten by final k_mlp):
    ushort_t* xb  = (ushort_t*)d_out;                        // [0, 25.6 MB)
    ushort_t* hrb = (ushort_t*)d_out + (size_t)NNODES * DIM; // [25.6, 51.2 MB)

    const int aggBlocks = NNODES / 16;              // 6250
    const int cvtBlocks = NNODES * DIM / (256 * 8); // 6250
    const int mlpBlocks = (NNODES + 63) / 64;       // 1563

    // ---- build CSR (bucketed counting sort) + weight prep + x->bf16 ----
    k_setup<<<1, 256, 0, stream>>>(ei, stats, flag, bcnt);
    k_bcount<<<256, 256, 0, stream>>>(ei, flag, bcnt);
    k_bscan<<<1, 256, 0, stream>>>(bcnt, bstart, bcur);
    k_bpair<<<256, 256, 0, stream>>>(ei, flag, bcur, pairs);
    k_bsort<<<NB_USED, 256, 0, stream>>>(pairs, bstart, C, ssrc);
    k_wprep<<<4, 256, 0, stream>>>(w1a, w1b, w2a, w2b, wbuf);
    k_xconv<<<cvtBlocks, 256, 0, stream>>>(x, xb);
    // ---- conv1 ----
    k_agg<false, true><<<aggBlocks, 256, 0, stream>>>(xb, x, zbuf, C, ssrc, nullptr, nullptr);
    k_mlp<true><<<mlpBlocks, 256, 0, stream>>>(
        zbuf, wbuf, wbuf + 32768, b1a, b1b, nullptr, hrb, stats);
    // ---- BN params ----
    k_bn<<<1, 128, 0, stream>>>(stats, gamma, beta);
    // ---- conv2 (BN affine folded into aggregate finalize) ----
    k_agg<true, false><<<aggBlocks, 256, 0, stream>>>(hrb, nullptr, zbuf, C, ssrc, stats, stats + DIM);
    k_mlp<false><<<mlpBlocks, 256, 0, stream>>>(
        zbuf, wbuf + 65536, wbuf + 98304, b2a, b2b, out, nullptr, nullptr);
}

// Round 6
// 317.055 us; speedup vs baseline: 19.3568x; 1.5453x over previous
//
#include <hip/hip_runtime.h>

#define NNODES 100000
#define NEDGES 1600000
#define DIM 128
#define BN_EPS 1e-5f
#define NBUCK 1024              // coarse buckets, dst>>7 -> 782 used
#define NB_USED ((NNODES + 127) / 128)   // 782

typedef unsigned int uint;
typedef unsigned short ushort_t;
using bhalf8  = __attribute__((ext_vector_type(8))) short;
using u16x8   = __attribute__((ext_vector_type(8))) unsigned short;
using f32x4_t = __attribute__((ext_vector_type(4))) float;

__device__ __forceinline__ float bf2f(uint u16) {
    return __uint_as_float(u16 << 16);
}
__device__ __forceinline__ uint pack2_bf16rn(float a, float b) {
    uint ua = __float_as_uint(a); ua += 0x7FFFu + ((ua >> 16) & 1u);
    uint ub = __float_as_uint(b); ub += 0x7FFFu + ((ub >> 16) & 1u);
    return __builtin_amdgcn_perm(ub, ua, 0x07060302u);  // {a.hi16, b.hi16}
}

// ---- edge access helper: flag=1 -> int64 layout, flag=0 -> int32 -----------
__device__ __forceinline__ int edge_src(const int* ei, int fl, int e) {
    return fl ? ei[2 * e] : ei[e];
}
__device__ __forceinline__ int edge_dst(const int* ei, int fl, int e) {
    return fl ? ei[2 * (NEDGES + e)] : ei[NEDGES + e];
}

// ---------------- setup: detect edge dtype + zero stats + zero bucket cnts --
__global__ __launch_bounds__(256) void k_setup(const int* __restrict__ ei,
                                               float* __restrict__ stats,
                                               int* __restrict__ flag,
                                               int* __restrict__ bcnt) {
    int t = threadIdx.x;
    stats[t] = 0.0f;  // sums[128] + sumsq[128]
    ((int4*)bcnt)[t] = make_int4(0, 0, 0, 0);
    if (t == 0) {
        int orr = 0;
        for (int i = 1; i < 128; i += 2) orr |= ei[i];
        *flag = (orr == 0) ? 1 : 0;
    }
}

// ---------------- pass 1: coarse bucket counts ------------------------------
__global__ __launch_bounds__(256) void k_bcount(const int* __restrict__ ei,
                                                const int* __restrict__ flag,
                                                int* __restrict__ bcnt) {
    __shared__ int h[NBUCK];
    int t = threadIdx.x;
    for (int i = t; i < NBUCK; i += 256) h[i] = 0;
    __syncthreads();
    int fl = *flag;
    int per = (NEDGES + gridDim.x - 1) / gridDim.x;
    int e0 = blockIdx.x * per;
    int e1 = min(e0 + per, NEDGES);
    for (int e = e0 + t; e < e1; e += 256)
        atomicAdd(&h[edge_dst(ei, fl, e) >> 7], 1);
    __syncthreads();
    for (int i = t; i < NBUCK; i += 256)
        if (h[i]) atomicAdd(&bcnt[i], h[i]);
}

// ---------------- pass 2: exscan of 1024 bucket counts ----------------------
__global__ __launch_bounds__(256) void k_bscan(const int* __restrict__ bcnt,
                                               int* __restrict__ bstart,
                                               int* __restrict__ bcur) {
    __shared__ int wtot[4];
    int t = threadIdx.x, lane = t & 63, w = t >> 6;
    int4 v = ((const int4*)bcnt)[t];
    int s = v.x + v.y + v.z + v.w;
    int sc = s;
#pragma unroll
    for (int d = 1; d < 64; d <<= 1) {
        int n = __shfl_up(sc, d, 64);
        if (lane >= d) sc += n;
    }
    if (lane == 63) wtot[w] = sc;
    __syncthreads();
    int woff = 0;
    for (int i = 0; i < w; ++i) woff += wtot[i];
    int excl = woff + sc - s;
    int o0 = excl, o1 = o0 + v.x, o2 = o1 + v.y, o3 = o2 + v.z;
    bstart[t * 4]     = o0;  bcur[t * 4]     = o0;
    bstart[t * 4 + 1] = o1;  bcur[t * 4 + 1] = o1;
    bstart[t * 4 + 2] = o2;  bcur[t * 4 + 2] = o2;
    bstart[t * 4 + 3] = o3;  bcur[t * 4 + 3] = o3;
    if (t == 255) bstart[NBUCK] = o3 + v.w;
}

// ---------------- pass 3: scatter packed (src<<7|dst&127) into buckets ------
__global__ __launch_bounds__(256) void k_bpair(const int* __restrict__ ei,
                                               const int* __restrict__ flag,
                                               int* __restrict__ bcur,
                                               int* __restrict__ pairs) {
    __shared__ int h[NBUCK];
    __shared__ int base[NBUCK];
    int t = threadIdx.x;
    for (int i = t; i < NBUCK; i += 256) h[i] = 0;
    __syncthreads();
    int fl = *flag;
    int per = (NEDGES + gridDim.x - 1) / gridDim.x;
    int e0 = blockIdx.x * per;
    int e1 = min(e0 + per, NEDGES);
    for (int e = e0 + t; e < e1; e += 256)
        atomicAdd(&h[edge_dst(ei, fl, e) >> 7], 1);
    __syncthreads();
    for (int i = t; i < NBUCK; i += 256) {
        int c = h[i];
        base[i] = c ? atomicAdd(&bcur[i], c) : 0;
    }
    __syncthreads();
    for (int i = t; i < NBUCK; i += 256) h[i] = 0;
    __syncthreads();
    for (int e = e0 + t; e < e1; e += 256) {
        int s = edge_src(ei, fl, e);
        int d = edge_dst(ei, fl, e);
        int b = d >> 7;
        int pos = atomicAdd(&h[b], 1);
        pairs[base[b] + pos] = (s << 7) | (d & 127);
    }
}

// ---------------- pass 4: per-bucket local sort -> ssrc + row ends ----------
__global__ __launch_bounds__(256) void k_bsort(const int* __restrict__ pairs,
                                               const int* __restrict__ bstart,
                                               int* __restrict__ C,
                                               int* __restrict__ ssrc) {
    __shared__ int cnt[128];
    __shared__ int off[128];
    int b = blockIdx.x;
    int t = threadIdx.x, lane = t & 63, w = t >> 6;
    int s = bstart[b], e = bstart[b + 1];
    if (t < 128) cnt[t] = 0;
    __syncthreads();
    for (int i = s + t; i < e; i += 256)
        atomicAdd(&cnt[pairs[i] & 127], 1);
    __syncthreads();
    if (w == 0) {   // wave-scan 128 bins
        int c0 = cnt[lane], c1 = cnt[64 + lane];
        int s0 = c0, s1 = c1;
#pragma unroll
        for (int d = 1; d < 64; d <<= 1) {
            int n0 = __shfl_up(s0, d, 64);
            int n1 = __shfl_up(s1, d, 64);
            if (lane >= d) { s0 += n0; s1 += n1; }
        }
        int tot0 = __shfl(s0, 63, 64);
        off[lane]      = s0 - c0;
        off[64 + lane] = tot0 + s1 - c1;
    }
    __syncthreads();
    if (t < 128) {
        int row = b * 128 + t;
        if (row < NNODES) C[row] = s + off[t] + cnt[t];
    }
    __syncthreads();
    for (int i = s + t; i < e; i += 256) {
        int p = pairs[i];
        int pos = atomicAdd(&off[p & 127], 1);
        ssrc[s + pos] = p >> 7;
    }
}

// ---------------- weight prep: fp32 [k][n] -> bf16-RN transposed [n][k] -----
__global__ __launch_bounds__(256) void k_wprep(const float* __restrict__ w0,
                                               const float* __restrict__ w1,
                                               const float* __restrict__ w2,
                                               const float* __restrict__ w3,
                                               ushort_t* __restrict__ ob) {
    const float* w = (blockIdx.x == 0) ? w0 : (blockIdx.x == 1) ? w1
                   : (blockIdx.x == 2) ? w2 : w3;
    ushort_t* oh = ob + (size_t)blockIdx.x * 16384;
    for (int i = threadIdx.x; i < 16384; i += 256) {
        int k = i >> 7, n = i & 127;
        uint u = __float_as_uint(w[i]);
        u += 0x7FFFu + ((u >> 16) & 1u);   // RN to bf16
        oh[n * 128 + k] = (ushort_t)(u >> 16);
    }
}

// ---------------- x (fp32) -> xb (bf16 RN) ----------------------------------
__global__ __launch_bounds__(256) void k_xconv(const float* __restrict__ X,
                                               ushort_t* __restrict__ Xb) {
    size_t i = ((size_t)blockIdx.x * 256 + threadIdx.x) * 8;
    float4 a = *(const float4*)(X + i);
    float4 b = *(const float4*)(X + i + 4);
    union { uint4 q; u16x8 v; } o;
    o.q.x = pack2_bf16rn(a.x, a.y);
    o.q.y = pack2_bf16rn(a.z, a.w);
    o.q.z = pack2_bf16rn(b.x, b.y);
    o.q.w = pack2_bf16rn(b.z, b.w);
    *(u16x8*)(Xb + i) = o.v;
}

// ---------------- split 8 fp32 -> bf16 hi (trunc) + bf16 lo ------------------
__device__ __forceinline__ void split8(const float4& f0, const float4& f1,
                                       bhalf8& h, bhalf8& l) {
    uint u[8] = { __float_as_uint(f0.x), __float_as_uint(f0.y),
                  __float_as_uint(f0.z), __float_as_uint(f0.w),
                  __float_as_uint(f1.x), __float_as_uint(f1.y),
                  __float_as_uint(f1.z), __float_as_uint(f1.w) };
    float fv[8] = { f0.x, f0.y, f0.z, f0.w, f1.x, f1.y, f1.z, f1.w };
    uint lu[8];
#pragma unroll
    for (int i = 0; i < 8; ++i) {
        float hf = __uint_as_float(u[i] & 0xffff0000u);
        lu[i] = __float_as_uint(fv[i] - hf);
    }
    union { uint4 q; bhalf8 s; } H, L;
    H.q.x = __builtin_amdgcn_perm(u[1], u[0], 0x07060302u);
    H.q.y = __builtin_amdgcn_perm(u[3], u[2], 0x07060302u);
    H.q.z = __builtin_amdgcn_perm(u[5], u[4], 0x07060302u);
    H.q.w = __builtin_amdgcn_perm(u[7], u[6], 0x07060302u);
    L.q.x = __builtin_amdgcn_perm(lu[1], lu[0], 0x07060302u);
    L.q.y = __builtin_amdgcn_perm(lu[3], lu[2], 0x07060302u);
    L.q.z = __builtin_amdgcn_perm(lu[5], lu[4], 0x07060302u);
    L.q.w = __builtin_amdgcn_perm(lu[7], lu[6], 0x07060302u);
    h = H.s; l = L.s;
}

// ---------------- gather-aggregate (bf16 neighbors) -------------------------
template <bool BN, bool SELF_F32>
__global__ __launch_bounds__(256) void k_agg(const ushort_t* __restrict__ Xb,
                                             const float* __restrict__ Xf,
                                             float* __restrict__ Z,
                                             const int* __restrict__ ends,
                                             const int* __restrict__ ssrc,
                                             const float* __restrict__ scale,
                                             const float* __restrict__ shift) {
    int t = threadIdx.x;
    int g = t >> 4;          // 0..15 row in block
    int l = t & 15;
    int row = blockIdx.x * 16 + g;
    int c8 = l * 8;
    int start = (row == 0) ? 0 : ends[row - 1];
    int end = ends[row];

    float acc[8];
    if (SELF_F32) {
        float4 a0 = *(const float4*)(Xf + (size_t)row * DIM + c8);
        float4 a1 = *(const float4*)(Xf + (size_t)row * DIM + c8 + 4);
        acc[0] = a0.x; acc[1] = a0.y; acc[2] = a0.z; acc[3] = a0.w;
        acc[4] = a1.x; acc[5] = a1.y; acc[6] = a1.z; acc[7] = a1.w;
    } else {
        union { u16x8 v; uint u[4]; } sv;
        sv.v = *(const u16x8*)(Xb + (size_t)row * DIM + c8);
#pragma unroll
        for (int i = 0; i < 4; ++i) {
            acc[2 * i]     = bf2f(sv.u[i] << 16 >> 16);
            acc[2 * i + 1] = __uint_as_float(sv.u[i] & 0xffff0000u);
        }
    }

    int e = start;
    for (; e + 7 < end; e += 8) {
        union { u16x8 v; uint u[4]; } nv[8];
#pragma unroll
        for (int i = 0; i < 8; ++i) {
            int s0 = ssrc[e + i];
            nv[i].v = *(const u16x8*)(Xb + (size_t)s0 * DIM + c8);
        }
#pragma unroll
        for (int i = 0; i < 8; ++i) {
#pragma unroll
            for (int j = 0; j < 4; ++j) {
                acc[2 * j]     += bf2f(nv[i].u[j] & 0xffffu);
                acc[2 * j + 1] += __uint_as_float(nv[i].u[j] & 0xffff0000u);
            }
        }
    }
    for (; e < end; ++e) {
        int s0 = ssrc[e];
        union { u16x8 v; uint u[4]; } nv;
        nv.v = *(const u16x8*)(Xb + (size_t)s0 * DIM + c8);
#pragma unroll
        for (int j = 0; j < 4; ++j) {
            acc[2 * j]     += bf2f(nv.u[j] & 0xffffu);
            acc[2 * j + 1] += __uint_as_float(nv.u[j] & 0xffff0000u);
        }
    }

    if (BN) {
        float4 sc0 = *(const float4*)(scale + c8);
        float4 sc1 = *(const float4*)(scale + c8 + 4);
        float4 sh0 = *(const float4*)(shift + c8);
        float4 sh1 = *(const float4*)(shift + c8 + 4);
        float cnt = (float)(end - start + 1);
        acc[0] = fmaf(acc[0], sc0.x, cnt * sh0.x);
        acc[1] = fmaf(acc[1], sc0.y, cnt * sh0.y);
        acc[2] = fmaf(acc[2], sc0.z, cnt * sh0.z);
        acc[3] = fmaf(acc[3], sc0.w, cnt * sh0.w);
        acc[4] = fmaf(acc[4], sc1.x, cnt * sh1.x);
        acc[5] = fmaf(acc[5], sc1.y, cnt * sh1.y);
        acc[6] = fmaf(acc[6], sc1.z, cnt * sh1.z);
        acc[7] = fmaf(acc[7], sc1.w, cnt * sh1.w);
    }
    float* zp = Z + (size_t)row * DIM + c8;
    *(float4*)zp       = make_float4(acc[0], acc[1], acc[2], acc[3]);
    *(float4*)(zp + 4) = make_float4(acc[4], acc[5], acc[6], acc[7]);
}

// ---------------- BN finalize: scale/shift from sums ------------------------
__global__ void k_bn(float* stats, const float* __restrict__ gamma,
                     const float* __restrict__ beta) {
    int c = threadIdx.x;  // 128 threads
    float s  = stats[c];
    float sq = stats[128 + c];
    float mean = s / (float)NNODES;
    float var  = sq / (float)NNODES - mean * mean;
    float sc = gamma[c] * rsqrtf(var + BN_EPS);
    float sh = beta[c] - mean * sc;
    stats[c]       = sc;
    stats[128 + c] = sh;
}

// ---------------- fused 2-layer MLP via split-bf16 MFMA, LDS weights --------
// 2-term split: acc = mfma(zh,wh) + mfma(zl,wh); weights bf16-RN in LDS.
// Weight LDS swizzle: 16B unit u at LDS unit u ^ ((u>>4)&7)  (G4 fix).
template <bool CONV1>
__global__ __launch_bounds__(256, 2) void k_mlp(const float* __restrict__ Z,
                                                const ushort_t* __restrict__ WAh,
                                                const ushort_t* __restrict__ WBh,
                                                const float* __restrict__ Ba,
                                                const float* __restrict__ Bb,
                                                float* __restrict__ OutF,
                                                ushort_t* __restrict__ OutB,
                                                float* __restrict__ stats) {
    __shared__ ushort_t wsl[16384];    // 32 KB: current layer's weights
    __shared__ float hbuf[64 * 128];   // 32 KB: mid, then output staging
    __shared__ float lsum[128], lsq[128];
    char* hb = (char*)hbuf;

    int t = threadIdx.x;
    int w = t >> 6, l = t & 63;
    int lr = l & 15;
    int lg = l >> 4;
    int slane = (lr & 7) << 4;
    if (CONV1 && t < 128) { lsum[t] = 0.f; lsq[t] = 0.f; }

    int rowBase = blockIdx.x * 64 + w * 16;
    bool active = rowBase < NNODES;

    // ---- stage Wa: linear global read -> swizzled LDS write ----
#pragma unroll
    for (int i = 0; i < 8; ++i) {
        int c = i * 256 + t;
        uint4 v = ((const uint4*)WAh)[c];
        ((uint4*)wsl)[c ^ ((c >> 4) & 7)] = v;
    }
    // ---- load z rows (HBM) + bias, overlapped with staging ----
    int zrow = active ? (rowBase + lr) : 0;
    const float* zp = Z + (size_t)zrow * 128 + lg * 8;
    float4 zf[8];
#pragma unroll
    for (int ks = 0; ks < 4; ++ks) {
        zf[2 * ks]     = *(const float4*)(zp + ks * 32);
        zf[2 * ks + 1] = *(const float4*)(zp + ks * 32 + 4);
    }
    f32x4_t acc[8];
#pragma unroll
    for (int nt = 0; nt < 8; ++nt) {
        float b = Ba[nt * 16 + lr];
        acc[nt][0] = b; acc[nt][1] = b; acc[nt][2] = b; acc[nt][3] = b;
    }
    bhalf8 zh[4], zl[4];
#pragma unroll
    for (int ks = 0; ks < 4; ++ks) split8(zf[2 * ks], zf[2 * ks + 1], zh[ks], zl[ks]);
    __syncthreads();   // Wa staged

    // ---- layer 1: mid = relu(Z @ Wa + Ba) ----
#pragma unroll
    for (int ks = 0; ks < 4; ++ks) {
#pragma unroll
        for (int nt = 0; nt < 8; ++nt) {
            int waddr = ((nt * 16 + lr) << 8) + ((((ks << 6) + (lg << 4))) ^ slane);
            bhalf8 wh = *(const bhalf8*)((const char*)wsl + waddr);
            acc[nt] = __builtin_amdgcn_mfma_f32_16x16x32_bf16(zh[ks], wh, acc[nt], 0, 0, 0);
            acc[nt] = __builtin_amdgcn_mfma_f32_16x16x32_bf16(zl[ks], wh, acc[nt], 0, 0, 0);
        }
    }
    // mid (relu) -> hbuf, transposed store, XOR-swizzled (bank-free, verified)
#pragma unroll
    for (int nt = 0; nt < 8; ++nt) {
#pragma unroll
        for (int j = 0; j < 4; ++j) {
            int rl = w * 16 + lg * 4 + j;
            int boff = (rl * 512 + (nt * 16 + lr) * 4) ^ ((rl & 7) << 4);
            *(float*)(hb + boff) = fmaxf(acc[nt][j], 0.f);
        }
    }
    __syncthreads();   // Wa reads + mid writes complete

    // ---- stage Wb over Wa; read mid from hbuf ----
#pragma unroll
    for (int i = 0; i < 8; ++i) {
        int c = i * 256 + t;
        uint4 v = ((const uint4*)WBh)[c];
        ((uint4*)wsl)[c ^ ((c >> 4) & 7)] = v;
    }
    {
        int rl = w * 16 + lr;
        int swz = (rl & 7) << 4;
        int rbase = rl * 512 + lg * 32;
        float4 mf[8];
#pragma unroll
        for (int ks = 0; ks < 4; ++ks) {
            mf[2 * ks]     = *(const float4*)(hb + ((rbase + ks * 128) ^ swz));
            mf[2 * ks + 1] = *(const float4*)(hb + ((rbase + ks * 128 + 16) ^ swz));
        }
#pragma unroll
        for (int ks = 0; ks < 4; ++ks) split8(mf[2 * ks], mf[2 * ks + 1], zh[ks], zl[ks]);
    }
#pragma unroll
    for (int nt = 0; nt < 8; ++nt) {
        float b = Bb[nt * 16 + lr];
        acc[nt][0] = b; acc[nt][1] = b; acc[nt][2] = b; acc[nt][3] = b;
    }
    __syncthreads();   // Wb staged, mid reads complete

    // ---- layer 2: out = mid @ Wb + Bb ----
#pragma unroll
    for (int ks = 0; ks < 4; ++ks) {
#pragma unroll
        for (int nt = 0; nt < 8; ++nt) {
            int waddr = ((nt * 16 + lr) << 8) + ((((ks << 6) + (lg << 4))) ^ slane);
            bhalf8 wh = *(const bhalf8*)((const char*)wsl + waddr);
            acc[nt] = __builtin_amdgcn_mfma_f32_16x16x32_bf16(zh[ks], wh, acc[nt], 0, 0, 0);
            acc[nt] = __builtin_amdgcn_mfma_f32_16x16x32_bf16(zl[ks], wh, acc[nt], 0, 0, 0);
        }
    }

    // ---- epilogue: relu + stats (CONV1), stage via LDS, coalesced store ----
    if (CONV1 && active) {
#pragma unroll
        for (int nt = 0; nt < 8; ++nt) {
            float s = 0.f, q = 0.f;
#pragma unroll
            for (int j = 0; j < 4; ++j) {
                float v = fmaxf(acc[nt][j], 0.f);
                acc[nt][j] = v;
                s += v; q += v * v;
            }
            s += __shfl_xor(s, 16); s += __shfl_xor(s, 32);
            q += __shfl_xor(q, 16); q += __shfl_xor(q, 32);
            if (l < 16) {
                atomicAdd(&lsum[nt * 16 + l], s);
                atomicAdd(&lsq[nt * 16 + l], q);
            }
        }
    }
    __syncthreads();   // everyone done reading mid from hbuf
#pragma unroll
    for (int nt = 0; nt < 8; ++nt) {
#pragma unroll
        for (int j = 0; j < 4; ++j) {
            int rl = w * 16 + lg * 4 + j;
            int boff = (rl * 512 + (nt * 16 + lr) * 4) ^ ((rl & 7) << 4);
            *(float*)(hb + boff) = acc[nt][j];
        }
    }
    if (CONV1) {
        __syncthreads();
        if (t < 128) {
            unsafeAtomicAdd(&stats[t], lsum[t]);
            unsafeAtomicAdd(&stats[128 + t], lsq[t]);
        }
    } else {
        __syncthreads();
    }
    // readback: 4 threads per row, 128 B each, coalesced global stores
    {
        int r2 = t >> 2;
        int row = blockIdx.x * 64 + r2;
        if (row < NNODES) {
            int sw2 = (r2 & 7) << 4;
            int ch0 = (t & 3) * 8;
            if (CONV1) {
#pragma unroll
                for (int c = 0; c < 8; c += 2) {
                    float4 v0 = *(const float4*)(hb + ((r2 * 512 + (ch0 + c) * 16) ^ sw2));
                    float4 v1 = *(const float4*)(hb + ((r2 * 512 + (ch0 + c + 1) * 16) ^ sw2));
                    union { uint4 q; u16x8 v; } o;
                    o.q.x = pack2_bf16rn(v0.x, v0.y);
                    o.q.y = pack2_bf16rn(v0.z, v0.w);
                    o.q.z = pack2_bf16rn(v1.x, v1.y);
                    o.q.w = pack2_bf16rn(v1.z, v1.w);
                    *(u16x8*)(OutB + (size_t)row * 128 + (ch0 + c) * 4) = o.v;
                }
            } else {
#pragma unroll
                for (int c = 0; c < 8; ++c) {
                    float4 v = *(const float4*)(hb + ((r2 * 512 + (ch0 + c) * 16) ^ sw2));
                    *(float4*)(OutF + (size_t)row * 128 + (ch0 + c) * 4) = v;
                }
            }
        }
    }
}

extern "C" void kernel_launch(void* const* d_in, const int* in_sizes, int n_in,
                              void* d_out, int out_size, void* d_ws, size_t ws_size,
                              hipStream_t stream) {
    const float* x     = (const float*)d_in[0];
    const int*   ei    = (const int*)d_in[1];
    const float* w1a   = (const float*)d_in[2];
    const float* b1a   = (const float*)d_in[3];
    const float* w1b   = (const float*)d_in[4];
    const float* b1b   = (const float*)d_in[5];
    const float* gamma = (const float*)d_in[6];
    const float* beta  = (const float*)d_in[7];
    const float* w2a   = (const float*)d_in[8];
    const float* b2a   = (const float*)d_in[9];
    const float* w2b   = (const float*)d_in[10];
    const float* b2b   = (const float*)d_in[11];
    float* out = (float*)d_out;

    char*     ws     = (char*)d_ws;
    float*    stats  = (float*)ws;                  // 256 floats
    int*      flag   = (int*)(ws + 1024);
    int*      bcnt   = (int*)(ws + 4096);           // 1024 ints
    int*      bstart = (int*)(ws + 8192);           // 1025 ints
    int*      bcur   = (int*)(ws + 16384);          // 1024 ints
    int*      C      = (int*)(ws + 404096);         // N ints (row ends)
    int*      ssrc   = (int*)(ws + 804096);         // E ints
    ushort_t* wbuf   = (ushort_t*)(ws + 0x700000);  // 4 x bf16-hi weights (128 KB)
    float*    zbuf   = (float*)(ws + 0x800000);     // N*D floats (51.2 MB)
    int*      pairs  = (int*)(ws + 0x800000);       // 6.4 MB, dead before zbuf use

    // bf16 scratch lives inside d_out (fully overwritten by final k_mlp):
    ushort_t* xb  = (ushort_t*)d_out;                        // [0, 25.6 MB)
    ushort_t* hrb = (ushort_t*)d_out + (size_t)NNODES * DIM; // [25.6, 51.2 MB)

    const int aggBlocks = NNODES / 16;              // 6250
    const int cvtBlocks = NNODES * DIM / (256 * 8); // 6250
    const int mlpBlocks = (NNODES + 63) / 64;       // 1563

    // ---- build CSR (bucketed counting sort) + weight prep + x->bf16 ----
    k_setup<<<1, 256, 0, stream>>>(ei, stats, flag, bcnt);
    k_bcount<<<256, 256, 0, stream>>>(ei, flag, bcnt);
    k_bscan<<<1, 256, 0, stream>>>(bcnt, bstart, bcur);
    k_bpair<<<256, 256, 0, stream>>>(ei, flag, bcur, pairs);
    k_bsort<<<NB_USED, 256, 0, stream>>>(pairs, bstart, C, ssrc);
    k_wprep<<<4, 256, 0, stream>>>(w1a, w1b, w2a, w2b, wbuf);
    k_xconv<<<cvtBlocks, 256, 0, stream>>>(x, xb);
    // ---- conv1 ----
    k_agg<false, true><<<aggBlocks, 256, 0, stream>>>(xb, x, zbuf, C, ssrc, nullptr, nullptr);
    k_mlp<true><<<mlpBlocks, 256, 0, stream>>>(
        zbuf, wbuf, wbuf + 16384, b1a, b1b, nullptr, hrb, stats);
    // ---- BN params ----
    k_bn<<<1, 128, 0, stream>>>(stats, gamma, beta);
    // ---- conv2 (BN affine folded into aggregate finalize) ----
    k_agg<true, false><<<aggBlocks, 256, 0, stream>>>(hrb, nullptr, zbuf, C, ssrc, stats, stats + DIM);
    k_mlp<false><<<mlpBlocks, 256, 0, stream>>>(
        zbuf, wbuf + 32768, wbuf + 49152, b2a, b2b, out, nullptr, nullptr);
}